// Round 1
// baseline (2614.119 us; speedup 1.0000x reference)
//
#include <hip/hip_runtime.h>
#include <math.h>
#include <float.h>

// dims
constexpr int NQ = 64, NK = 256, SSZ = 64, D = 512, FF = 2048;
constexpr int PAIRS = NQ * NK;          // 16384
constexpr int ROWSX = 2 * PAIRS;        // 32768

// ---------------- K0: sigmoid of score_embed (or 1.0 if !flag) -------------
__global__ void k_sig(const float* __restrict__ se, const int* __restrict__ flag,
                      float* __restrict__ sig) {
    int i = blockIdx.x * blockDim.x + threadIdx.x;
    if (i < SSZ * SSZ) {
        sig[i] = (*flag) ? 1.0f / (1.0f + expf(-se[i])) : 1.0f;
    }
}

// ---------------- K1: QK = [tgt;mem] @ W1^T + b1 (or copy if !flag) --------
// C[m][n] = sum_k X[m][k] * W1[n][k] + b1[n].  m in [0,20480), n in [0,512)
__global__ __launch_bounds__(256) void k_gemm1(
        const float* __restrict__ tgt, const float* __restrict__ mem,
        const float* __restrict__ W1, const float* __restrict__ b1,
        const int* __restrict__ flag, float* __restrict__ C) {
    int bm = blockIdx.x >> 3, bn = blockIdx.x & 7;
    int m0 = bm * 64, n0 = bn * 64;
    const float* X = (m0 < NQ * SSZ) ? (tgt + (size_t)m0 * D)
                                     : (mem + (size_t)(m0 - NQ * SSZ) * D);
    int tid = threadIdx.x;
    if (!(*flag)) {
        for (int u = 0; u < 16; ++u) {
            int e = u * 256 + tid;
            int r = e >> 6, c = e & 63;
            C[(size_t)(m0 + r) * D + n0 + c] = X[(size_t)r * D + n0 + c];
        }
        return;
    }
    __shared__ float As[64][68];
    __shared__ float Bs[64][68];
    int tx = tid & 15, ty = tid >> 4;
    int lr = tid >> 2, lq = tid & 3;
    float acc[4][4] = {};
    for (int kb = 0; kb < D; kb += 64) {
        const float* Ab = X + (size_t)lr * D + kb;
        const float* Bb = W1 + (size_t)(n0 + lr) * D + kb;
#pragma unroll
        for (int u = 0; u < 4; ++u) {
            int c = (lq + 4 * u) * 4;
            *reinterpret_cast<float4*>(&As[lr][c]) = *reinterpret_cast<const float4*>(&Ab[c]);
            *reinterpret_cast<float4*>(&Bs[lr][c]) = *reinterpret_cast<const float4*>(&Bb[c]);
        }
        __syncthreads();
#pragma unroll
        for (int k4 = 0; k4 < 16; ++k4) {
            float4 a[4], b[4];
#pragma unroll
            for (int i = 0; i < 4; ++i) a[i] = *reinterpret_cast<const float4*>(&As[ty + 16 * i][k4 * 4]);
#pragma unroll
            for (int j = 0; j < 4; ++j) b[j] = *reinterpret_cast<const float4*>(&Bs[tx + 16 * j][k4 * 4]);
#pragma unroll
            for (int i = 0; i < 4; ++i)
#pragma unroll
                for (int j = 0; j < 4; ++j)
                    acc[i][j] += a[i].x * b[j].x + a[i].y * b[j].y
                               + a[i].z * b[j].z + a[i].w * b[j].w;
        }
        __syncthreads();
    }
#pragma unroll
    for (int i = 0; i < 4; ++i)
#pragma unroll
        for (int j = 0; j < 4; ++j)
            C[(size_t)(m0 + ty + 16 * i) * D + n0 + tx + 16 * j] =
                acc[i][j] + b1[n0 + tx + 16 * j];
}

// ---------------- K2: fused score einsum + sigmoid + dual max --------------
// per block: pair p = qi*256+ki.  score[s][t] = dot(query[qi][t], key[ki][s]) * sig[s][t]
// out rows: xbuf[2p][t] = max_s,  xbuf[2p+1][s] = max_t
__global__ __launch_bounds__(256) void k_score(
        const float* __restrict__ QK, const float* __restrict__ sig,
        float* __restrict__ xbuf) {
    int p = blockIdx.x;
    int qi = p >> 8, ki = p & 255;
    const float* A = QK + (size_t)qi * SSZ * D;                 // query rows t
    const float* B = QK + (size_t)(NQ * SSZ + ki * SSZ) * D;    // key rows s
    __shared__ float As[64][68];
    __shared__ float Bs[64][68];
    __shared__ float part1[16][64];
    __shared__ float part2[16][64];
    int tid = threadIdx.x;
    int tx = tid & 15, ty = tid >> 4;
    int lr = tid >> 2, lq = tid & 3;
    float acc[4][4] = {};
    for (int kb = 0; kb < D; kb += 64) {
        const float* Ab = A + (size_t)lr * D + kb;
        const float* Bb = B + (size_t)lr * D + kb;
#pragma unroll
        for (int u = 0; u < 4; ++u) {
            int c = (lq + 4 * u) * 4;
            *reinterpret_cast<float4*>(&As[lr][c]) = *reinterpret_cast<const float4*>(&Ab[c]);
            *reinterpret_cast<float4*>(&Bs[lr][c]) = *reinterpret_cast<const float4*>(&Bb[c]);
        }
        __syncthreads();
#pragma unroll
        for (int k4 = 0; k4 < 16; ++k4) {
            float4 a[4], b[4];
#pragma unroll
            for (int i = 0; i < 4; ++i) a[i] = *reinterpret_cast<const float4*>(&As[ty + 16 * i][k4 * 4]);
#pragma unroll
            for (int j = 0; j < 4; ++j) b[j] = *reinterpret_cast<const float4*>(&Bs[tx + 16 * j][k4 * 4]);
#pragma unroll
            for (int i = 0; i < 4; ++i)
#pragma unroll
                for (int j = 0; j < 4; ++j)
                    acc[i][j] += a[i].x * b[j].x + a[i].y * b[j].y
                               + a[i].z * b[j].z + a[i].w * b[j].w;
        }
        __syncthreads();
    }
    // epilogue: t = ty + 16i, s = tx + 16j
    float pmt[4] = {-FLT_MAX, -FLT_MAX, -FLT_MAX, -FLT_MAX};
    float pms[4] = {-FLT_MAX, -FLT_MAX, -FLT_MAX, -FLT_MAX};
#pragma unroll
    for (int i = 0; i < 4; ++i)
#pragma unroll
        for (int j = 0; j < 4; ++j) {
            int t = ty + 16 * i, s = tx + 16 * j;
            float val = acc[i][j] * sig[s * 64 + t];
            pmt[i] = fmaxf(pmt[i], val);
            pms[j] = fmaxf(pms[j], val);
        }
#pragma unroll
    for (int i = 0; i < 4; ++i) part1[tx][ty + 16 * i] = pmt[i];
#pragma unroll
    for (int j = 0; j < 4; ++j) part2[ty][tx + 16 * j] = pms[j];
    __syncthreads();
    if (tid < 64) {
        float m = part1[0][tid];
#pragma unroll
        for (int e = 1; e < 16; ++e) m = fmaxf(m, part1[e][tid]);
        xbuf[(size_t)(2 * p) * 64 + tid] = m;
    } else if (tid < 128) {
        int s = tid - 64;
        float m = part2[0][s];
#pragma unroll
        for (int e = 1; e < 16; ++e) m = fmaxf(m, part2[e][s]);
        xbuf[(size_t)(2 * p + 1) * 64 + s] = m;
    }
}

// ---------------- K3: row stats S1[64], S2[64][64] over xbuf ---------------
__global__ __launch_bounds__(256) void k_stats1(const float* __restrict__ xbuf,
        double* __restrict__ S1d, double* __restrict__ S2d) {
    __shared__ float xr[4][64];
    int tid = threadIdx.x;
    int row0 = blockIdx.x * 512;
    float acc[16] = {};
    float s1 = 0.f;
    int pbase = tid * 16;
    for (int it = 0; it < 128; ++it) {
        int r = row0 + it * 4;
        xr[tid >> 6][tid & 63] = xbuf[(size_t)(r + (tid >> 6)) * 64 + (tid & 63)];
        __syncthreads();
#pragma unroll
        for (int e = 0; e < 16; ++e) {
            int a = (pbase + e) >> 6, b = (pbase + e) & 63;
            acc[e] += xr[0][a] * xr[0][b] + xr[1][a] * xr[1][b]
                    + xr[2][a] * xr[2][b] + xr[3][a] * xr[3][b];
        }
        if (tid < 64) s1 += xr[0][tid] + xr[1][tid] + xr[2][tid] + xr[3][tid];
        __syncthreads();
    }
#pragma unroll
    for (int e = 0; e < 16; ++e) atomicAdd(&S2d[pbase + e], (double)acc[e]);
    if (tid < 64) atomicAdd(&S1d[tid], (double)s1);
}

// ---------------- K4: finalize BN1 + normalized mean/cov -------------------
__global__ __launch_bounds__(256) void k_fin1(
        const double* __restrict__ S1d, const double* __restrict__ S2d,
        const float* __restrict__ g1, const float* __restrict__ be1,
        float* __restrict__ bn1, float* __restrict__ xbarn, float* __restrict__ covn) {
    int tid = threadIdx.x;
    double sum = 0.0, sumsq = 0.0;
    for (int j = 0; j < 64; ++j) { sum += S1d[j]; sumsq += S2d[j * 64 + j]; }
    const double Nall = (double)ROWSX * 64.0;
    double m1 = sum / Nall;
    double var1 = sumsq / Nall - m1 * m1;
    double scaled = (double)g1[0] / sqrt(var1 + 1e-5);
    if (tid == 0) { bn1[0] = (float)m1; bn1[1] = (float)scaled; }
    const double Rinv = 1.0 / (double)ROWSX;
    if (tid < 64) xbarn[tid] = (float)((S1d[tid] * Rinv - m1) * scaled) + be1[0];
#pragma unroll
    for (int e = 0; e < 16; ++e) {
        int idx = tid * 16 + e;
        int a = idx >> 6, b = idx & 63;
        double cov = S2d[idx] * Rinv - (S1d[a] * Rinv) * (S1d[b] * Rinv);
        covn[idx] = (float)(cov * scaled * scaled);
    }
}

// ---------------- K5: analytic BN2 stats per feature -----------------------
// m2[f] = W2[f].xbarn + b2[f];  var2[f] = W2[f]^T Covn W2[f];  t2 = g2*rsqrt(var+eps)
__global__ __launch_bounds__(64) void k_bn2(
        const float* __restrict__ covn, const float* __restrict__ xbarn,
        const float* __restrict__ W2, const float* __restrict__ b2,
        const float* __restrict__ g2, float* __restrict__ m2, float* __restrict__ t2) {
    int f = blockIdx.x;
    int j = threadIdx.x;
    float wj = W2[(size_t)f * 64 + j];
    float t1 = 0.f;
    for (int b = 0; b < 64; ++b) t1 += covn[j * 64 + b] * W2[(size_t)f * 64 + b];
    float vc = wj * t1;
    float mc = wj * xbarn[j];
#pragma unroll
    for (int off = 32; off; off >>= 1) {
        vc += __shfl_down(vc, off);
        mc += __shfl_down(mc, off);
    }
    if (j == 0) {
        m2[f] = mc + b2[f];
        t2[f] = g2[f] * rsqrtf(vc + 1e-5f);
    }
}

// ---------------- K6: fused BN1-apply + GEMM2 + BN2 + relu + W3 dot --------
__global__ __launch_bounds__(256) void k_mlp(
        const float* __restrict__ xbuf, const float* __restrict__ bn1,
        const float* __restrict__ be1,
        const float* __restrict__ W2, const float* __restrict__ m2,
        const float* __restrict__ t2, const float* __restrict__ be2,
        const float* __restrict__ W3, const float* __restrict__ b3,
        float* __restrict__ z) {
    __shared__ float Xs[64][68];
    __shared__ float Ws[64][68];
    __shared__ float mcs[64], tcs[64], becs[64], w3s[64];
    __shared__ float part[16][64];
    int tid = threadIdx.x;
    int r0 = blockIdx.x * 64;
    float m1 = bn1[0], sc = bn1[1], sh = be1[0];
    int lr = tid >> 2, lq = tid & 3;
    {
        const float* Xb = xbuf + (size_t)(r0 + lr) * 64;
#pragma unroll
        for (int u = 0; u < 4; ++u) {
            int c = (lq + 4 * u) * 4;
            float4 xv = *reinterpret_cast<const float4*>(&Xb[c]);
            xv.x = (xv.x - m1) * sc + sh;
            xv.y = (xv.y - m1) * sc + sh;
            xv.z = (xv.z - m1) * sc + sh;
            xv.w = (xv.w - m1) * sc + sh;
            *reinterpret_cast<float4*>(&Xs[lr][c]) = xv;
        }
    }
    int tx = tid & 15, ty = tid >> 4;
    float zacc[4] = {};
    for (int fc = 0; fc < FF; fc += 64) {
        const float* Wb = W2 + (size_t)(fc + lr) * 64;
#pragma unroll
        for (int u = 0; u < 4; ++u) {
            int c = (lq + 4 * u) * 4;
            *reinterpret_cast<float4*>(&Ws[lr][c]) = *reinterpret_cast<const float4*>(&Wb[c]);
        }
        if (tid < 64) {
            mcs[tid] = m2[fc + tid]; tcs[tid] = t2[fc + tid];
            becs[tid] = be2[fc + tid]; w3s[tid] = W3[fc + tid];
        }
        __syncthreads();
        float acc[4][4] = {};
#pragma unroll
        for (int k4 = 0; k4 < 16; ++k4) {
            float4 a[4], b[4];
#pragma unroll
            for (int i = 0; i < 4; ++i) a[i] = *reinterpret_cast<const float4*>(&Xs[ty + 16 * i][k4 * 4]);
#pragma unroll
            for (int j = 0; j < 4; ++j) b[j] = *reinterpret_cast<const float4*>(&Ws[tx + 16 * j][k4 * 4]);
#pragma unroll
            for (int i = 0; i < 4; ++i)
#pragma unroll
                for (int j = 0; j < 4; ++j)
                    acc[i][j] += a[i].x * b[j].x + a[i].y * b[j].y
                               + a[i].z * b[j].z + a[i].w * b[j].w;
        }
#pragma unroll
        for (int j = 0; j < 4; ++j) {
            int f = tx + 16 * j;
            float mcf = mcs[f], tcf = tcs[f], bef = becs[f], w3f = w3s[f];
#pragma unroll
            for (int i = 0; i < 4; ++i) {
                float yb = (acc[i][j] - mcf) * tcf + bef;
                zacc[i] += fmaxf(yb, 0.f) * w3f;
            }
        }
        __syncthreads();
    }
#pragma unroll
    for (int i = 0; i < 4; ++i) part[tx][ty + 16 * i] = zacc[i];
    __syncthreads();
    if (tid < 64) {
        float s = 0.f;
#pragma unroll
        for (int e = 0; e < 16; ++e) s += part[e][tid];
        z[r0 + tid] = s + b3[0];
    }
}

// ---------------- K7: pair-sum + BN3 stats ---------------------------------
__global__ __launch_bounds__(256) void k_pair(const float* __restrict__ z,
        float* __restrict__ v, double* __restrict__ sums3) {
    int i = blockIdx.x * 256 + threadIdx.x;
    float val = z[2 * i] + z[2 * i + 1];
    v[i] = val;
    float s = val, ss = val * val;
#pragma unroll
    for (int off = 32; off; off >>= 1) {
        s += __shfl_down(s, off);
        ss += __shfl_down(ss, off);
    }
    __shared__ float bs[4], bss[4];
    int lane = threadIdx.x & 63, w = threadIdx.x >> 6;
    if (lane == 0) { bs[w] = s; bss[w] = ss; }
    __syncthreads();
    if (threadIdx.x == 0) {
        atomicAdd(&sums3[0], (double)(bs[0] + bs[1] + bs[2] + bs[3]));
        atomicAdd(&sums3[1], (double)(bss[0] + bss[1] + bss[2] + bss[3]));
    }
}

// ---------------- K8: finalize BN3 -----------------------------------------
__global__ void k_fin3(const double* __restrict__ sums3, const float* __restrict__ g3,
                       float* __restrict__ bn3) {
    double m = sums3[0] / (double)PAIRS;
    double var = sums3[1] / (double)PAIRS - m * m;
    bn3[0] = (float)m;
    bn3[1] = (float)((double)g3[0] / sqrt(var + 1e-5));
}

// ---------------- K9: write output -----------------------------------------
__global__ void k_out(const float* __restrict__ v, const float* __restrict__ bn3,
                      const float* __restrict__ be3, float* __restrict__ out) {
    int i = blockIdx.x * 256 + threadIdx.x;
    if (i < PAIRS) out[i] = (v[i] - bn3[0]) * bn3[1] + be3[0];
}

extern "C" void kernel_launch(void* const* d_in, const int* in_sizes, int n_in,
                              void* d_out, int out_size, void* d_ws, size_t ws_size,
                              hipStream_t stream) {
    (void)in_sizes; (void)n_in; (void)out_size; (void)ws_size;
    const float* tgt = (const float*)d_in[0];
    const float* mem = (const float*)d_in[1];
    const float* W1  = (const float*)d_in[2];
    const float* b1  = (const float*)d_in[3];
    const float* se  = (const float*)d_in[4];
    const float* W2  = (const float*)d_in[5];
    const float* b2  = (const float*)d_in[6];
    const float* W3  = (const float*)d_in[7];
    const float* b3  = (const float*)d_in[8];
    const float* g1  = (const float*)d_in[9];
    const float* be1 = (const float*)d_in[10];
    const float* g2  = (const float*)d_in[11];
    const float* be2 = (const float*)d_in[12];
    const float* g3  = (const float*)d_in[13];
    const float* be3 = (const float*)d_in[14];
    const int*  flag = (const int*)d_in[15];
    float* out = (float*)d_out;

    char* ws = (char*)d_ws;
    size_t off = 0;
    auto alloc = [&](size_t bytes) -> void* {
        void* p = ws + off;
        off = (off + bytes + 255) & ~(size_t)255;
        return p;
    };
    float* sig   = (float*)alloc((size_t)SSZ * SSZ * 4);
    float* QK    = (float*)alloc((size_t)(NQ + NK) * SSZ * D * 4);   // 40 MB
    float* xbuf  = (float*)alloc((size_t)ROWSX * 64 * 4);            // 8 MB
    float* z     = (float*)alloc((size_t)ROWSX * 4);
    float* v     = (float*)alloc((size_t)PAIRS * 4);
    float* m2    = (float*)alloc((size_t)FF * 4);
    float* t2    = (float*)alloc((size_t)FF * 4);
    float* xbarn = (float*)alloc(64 * 4);
    float* covn  = (float*)alloc(64 * 64 * 4);
    float* bn1   = (float*)alloc(16);
    float* bn3   = (float*)alloc(16);
    size_t statsStart = off;
    double* S1d   = (double*)alloc(64 * 8);
    double* S2d   = (double*)alloc(64 * 64 * 8);
    double* sums3 = (double*)alloc(2 * 8);
    size_t statsEnd = off;

    hipMemsetAsync(ws + statsStart, 0, statsEnd - statsStart, stream);

    k_sig<<<16, 256, 0, stream>>>(se, flag, sig);
    k_gemm1<<<((NQ + NK) * SSZ / 64) * (D / 64), 256, 0, stream>>>(tgt, mem, W1, b1, flag, QK);
    k_score<<<PAIRS, 256, 0, stream>>>(QK, sig, xbuf);
    k_stats1<<<64, 256, 0, stream>>>(xbuf, S1d, S2d);
    k_fin1<<<1, 256, 0, stream>>>(S1d, S2d, g1, be1, bn1, xbarn, covn);
    k_bn2<<<FF, 64, 0, stream>>>(covn, xbarn, W2, b2, g2, m2, t2);
    k_mlp<<<ROWSX / 64, 256, 0, stream>>>(xbuf, bn1, be1, W2, m2, t2, be2, W3, b3, z);
    k_pair<<<PAIRS / 256, 256, 0, stream>>>(z, v, sums3);
    k_fin3<<<1, 1, 0, stream>>>(sums3, g3, bn3);
    k_out<<<PAIRS / 256, 256, 0, stream>>>(v, bn3, be3, out);
}

// Round 2
// 772.153 us; speedup vs baseline: 3.3855x; 3.3855x over previous
//
#include <hip/hip_runtime.h>
#include <hip/hip_bf16.h>
#include <math.h>
#include <float.h>

// dims
constexpr int NQ = 64, NK = 256, SSZ = 64, D = 512, FF = 2048;
constexpr int PAIRS = NQ * NK;          // 16384
constexpr int ROWSX = 2 * PAIRS;        // 32768

typedef __bf16 bf16x8 __attribute__((ext_vector_type(8)));
typedef float floatx16 __attribute__((ext_vector_type(16)));

// ---------------- K0: sigmoid of score_embed (or 1.0 if !flag) -------------
__global__ void k_sig(const float* __restrict__ se, const int* __restrict__ flag,
                      float* __restrict__ sig) {
    int i = blockIdx.x * blockDim.x + threadIdx.x;
    if (i < SSZ * SSZ) {
        sig[i] = (*flag) ? 1.0f / (1.0f + expf(-se[i])) : 1.0f;
    }
}

// ---------------- K1: QK = [tgt;mem] @ W1^T + b1 (or copy if !flag) --------
// fp32 compute, bf16 output. C[m][n] = sum_k X[m][k]*W1[n][k] + b1[n]
__global__ __launch_bounds__(256) void k_gemm1(
        const float* __restrict__ tgt, const float* __restrict__ mem,
        const float* __restrict__ W1, const float* __restrict__ b1,
        const int* __restrict__ flag, __hip_bfloat16* __restrict__ C) {
    int bm = blockIdx.x >> 3, bn = blockIdx.x & 7;
    int m0 = bm * 64, n0 = bn * 64;
    const float* X = (m0 < NQ * SSZ) ? (tgt + (size_t)m0 * D)
                                     : (mem + (size_t)(m0 - NQ * SSZ) * D);
    int tid = threadIdx.x;
    if (!(*flag)) {
        for (int u = 0; u < 16; ++u) {
            int e = u * 256 + tid;
            int r = e >> 6, c = e & 63;
            C[(size_t)(m0 + r) * D + n0 + c] = __float2bfloat16(X[(size_t)r * D + n0 + c]);
        }
        return;
    }
    __shared__ float As[64][68];
    __shared__ float Bs[64][68];
    int tx = tid & 15, ty = tid >> 4;
    int lr = tid >> 2, lq = tid & 3;
    float acc[4][4] = {};
    for (int kb = 0; kb < D; kb += 64) {
        const float* Ab = X + (size_t)lr * D + kb;
        const float* Bb = W1 + (size_t)(n0 + lr) * D + kb;
#pragma unroll
        for (int u = 0; u < 4; ++u) {
            int c = (lq + 4 * u) * 4;
            *reinterpret_cast<float4*>(&As[lr][c]) = *reinterpret_cast<const float4*>(&Ab[c]);
            *reinterpret_cast<float4*>(&Bs[lr][c]) = *reinterpret_cast<const float4*>(&Bb[c]);
        }
        __syncthreads();
#pragma unroll
        for (int k4 = 0; k4 < 16; ++k4) {
            float4 a[4], b[4];
#pragma unroll
            for (int i = 0; i < 4; ++i) a[i] = *reinterpret_cast<const float4*>(&As[ty + 16 * i][k4 * 4]);
#pragma unroll
            for (int j = 0; j < 4; ++j) b[j] = *reinterpret_cast<const float4*>(&Bs[tx + 16 * j][k4 * 4]);
#pragma unroll
            for (int i = 0; i < 4; ++i)
#pragma unroll
                for (int j = 0; j < 4; ++j)
                    acc[i][j] += a[i].x * b[j].x + a[i].y * b[j].y
                               + a[i].z * b[j].z + a[i].w * b[j].w;
        }
        __syncthreads();
    }
#pragma unroll
    for (int i = 0; i < 4; ++i)
#pragma unroll
        for (int j = 0; j < 4; ++j)
            C[(size_t)(m0 + ty + 16 * i) * D + n0 + tx + 16 * j] =
                __float2bfloat16(acc[i][j] + b1[n0 + tx + 16 * j]);
}

// ---------------- K2: MFMA score einsum + sigmoid + dual max ---------------
// block = 4 waves; wave w handles pair p = qi*256 + (kg*4+w).
// All waves share the Q tile (rows qi*64..), each wave has its own K tile.
// score[s][t] = dot(K[ki][s][:], Q[qi][t][:]) * sig[s][t]
// xbuf[2p][t] = max_s, xbuf[2p+1][s] = max_t
__global__ __launch_bounds__(256, 2) void k_score_mfma(
        const __hip_bfloat16* __restrict__ QKb, const float* __restrict__ sig,
        float* __restrict__ xbuf) {
    constexpr int LDR = 72;  // padded row: 72 bf16 = 144 B = 9 x 16B chunks
    __shared__ __attribute__((aligned(16))) unsigned short lds[5 * 64 * LDR]; // 46080 B
    const unsigned short* QKu = reinterpret_cast<const unsigned short*>(QKb);

    int tid = threadIdx.x;
    int w = tid >> 6;          // wave 0..3
    int l = tid & 63;          // lane
    int h = l >> 5;            // half
    int c = l & 31;            // col within 32

    int qi = blockIdx.x >> 6;
    int kg = blockIdx.x & 63;

    floatx16 acc00 = {}, acc01 = {}, acc10 = {}, acc11 = {};

    for (int kb = 0; kb < D; kb += 64) {
        // ---- stage 5 tiles: tile 0 = Q rows qi*64.., tile 1+j = K rows 4096+(kg*4+j)*64
#pragma unroll
        for (int i = 0; i < 10; ++i) {
            int slot = i * 256 + tid;          // 0..2559
            int tile = slot >> 9;
            int s512 = slot & 511;
            int row = s512 >> 3, c8 = s512 & 7;
            int grow = (tile == 0) ? (qi * 64 + row)
                                   : (NQ * SSZ + (kg * 4 + tile - 1) * 64 + row);
            uint4 v = *reinterpret_cast<const uint4*>(QKu + (size_t)grow * D + kb + c8 * 8);
            *reinterpret_cast<uint4*>(&lds[(tile * 64 + row) * LDR + c8 * 8]) = v;
        }
        __syncthreads();
        const unsigned short* ldsQ = &lds[0];
        const unsigned short* ldsK = &lds[(1 + w) * 64 * LDR];
#pragma unroll
        for (int st = 0; st < 4; ++st) {
            int d = st * 16 + h * 8;
            bf16x8 a0 = *reinterpret_cast<const bf16x8*>(ldsK + (c) * LDR + d);
            bf16x8 a1 = *reinterpret_cast<const bf16x8*>(ldsK + (32 + c) * LDR + d);
            bf16x8 b0 = *reinterpret_cast<const bf16x8*>(ldsQ + (c) * LDR + d);
            bf16x8 b1 = *reinterpret_cast<const bf16x8*>(ldsQ + (32 + c) * LDR + d);
            acc00 = __builtin_amdgcn_mfma_f32_32x32x16_bf16(a0, b0, acc00, 0, 0, 0);
            acc01 = __builtin_amdgcn_mfma_f32_32x32x16_bf16(a0, b1, acc01, 0, 0, 0);
            acc10 = __builtin_amdgcn_mfma_f32_32x32x16_bf16(a1, b0, acc10, 0, 0, 0);
            acc11 = __builtin_amdgcn_mfma_f32_32x32x16_bf16(a1, b1, acc11, 0, 0, 0);
        }
        __syncthreads();
    }

    // ---- stage sig into LDS (4096 floats = 16 KB)
    float* sigl = reinterpret_cast<float*>(lds);
#pragma unroll
    for (int i = 0; i < 4; ++i) {
        int idx = i * 256 + tid;
        *reinterpret_cast<float4*>(sigl + idx * 4) =
            *reinterpret_cast<const float4*>(sig + idx * 4);
    }
    __syncthreads();

    // ---- epilogue: val = acc * sig; track max over s (per t) and max over t (per s)
    // C/D layout: col(t') = c, row(s') = (r&3) + 8*(r>>2) + 4*h
    int p = qi * 256 + kg * 4 + w;
    float tmax0 = -FLT_MAX, tmax1 = -FLT_MAX;
    float smax[2][16];
#pragma unroll
    for (int si = 0; si < 2; ++si) {
        const floatx16& A0 = si ? acc10 : acc00;   // ti = 0
        const floatx16& A1 = si ? acc11 : acc01;   // ti = 1
#pragma unroll
        for (int r = 0; r < 16; ++r) {
            int srow = si * 32 + (r & 3) + 8 * (r >> 2) + 4 * h;
            float v0 = A0[r] * sigl[srow * 64 + c];
            float v1 = A1[r] * sigl[srow * 64 + 32 + c];
            tmax0 = fmaxf(tmax0, v0);
            tmax1 = fmaxf(tmax1, v1);
            smax[si][r] = fmaxf(v0, v1);
        }
    }
    // max over s: combine lane pairs l, l^32 (together they cover all 32 rows/quad)
    tmax0 = fmaxf(tmax0, __shfl_xor(tmax0, 32, 64));
    tmax1 = fmaxf(tmax1, __shfl_xor(tmax1, 32, 64));
    if (h == 0) {
        xbuf[(size_t)(2 * p) * 64 + c] = tmax0;
        xbuf[(size_t)(2 * p) * 64 + 32 + c] = tmax1;
    }
    // max over t: butterfly across the 32 cols (lanes within same half)
#pragma unroll
    for (int stage = 1; stage < 32; stage <<= 1) {
#pragma unroll
        for (int si = 0; si < 2; ++si)
#pragma unroll
            for (int r = 0; r < 16; ++r)
                smax[si][r] = fmaxf(smax[si][r], __shfl_xor(smax[si][r], stage, 64));
    }
    if (c == 0) {
#pragma unroll
        for (int si = 0; si < 2; ++si)
#pragma unroll
            for (int r = 0; r < 16; ++r) {
                int srow = si * 32 + (r & 3) + 8 * (r >> 2) + 4 * h;
                xbuf[(size_t)(2 * p + 1) * 64 + srow] = smax[si][r];
            }
    }
}

// ---------------- K3: row stats S1[64], S2[64][64] over xbuf ---------------
__global__ __launch_bounds__(256) void k_stats1(const float* __restrict__ xbuf,
        double* __restrict__ S1d, double* __restrict__ S2d) {
    __shared__ float xr[4][64];
    int tid = threadIdx.x;
    int row0 = blockIdx.x * 512;
    float acc[16] = {};
    float s1 = 0.f;
    int pbase = tid * 16;
    for (int it = 0; it < 128; ++it) {
        int r = row0 + it * 4;
        xr[tid >> 6][tid & 63] = xbuf[(size_t)(r + (tid >> 6)) * 64 + (tid & 63)];
        __syncthreads();
#pragma unroll
        for (int e = 0; e < 16; ++e) {
            int a = (pbase + e) >> 6, b = (pbase + e) & 63;
            acc[e] += xr[0][a] * xr[0][b] + xr[1][a] * xr[1][b]
                    + xr[2][a] * xr[2][b] + xr[3][a] * xr[3][b];
        }
        if (tid < 64) s1 += xr[0][tid] + xr[1][tid] + xr[2][tid] + xr[3][tid];
        __syncthreads();
    }
#pragma unroll
    for (int e = 0; e < 16; ++e) atomicAdd(&S2d[pbase + e], (double)acc[e]);
    if (tid < 64) atomicAdd(&S1d[tid], (double)s1);
}

// ---------------- K4: finalize BN1 + normalized mean/cov -------------------
__global__ __launch_bounds__(256) void k_fin1(
        const double* __restrict__ S1d, const double* __restrict__ S2d,
        const float* __restrict__ g1, const float* __restrict__ be1,
        float* __restrict__ bn1, float* __restrict__ xbarn, float* __restrict__ covn) {
    int tid = threadIdx.x;
    double sum = 0.0, sumsq = 0.0;
    for (int j = 0; j < 64; ++j) { sum += S1d[j]; sumsq += S2d[j * 64 + j]; }
    const double Nall = (double)ROWSX * 64.0;
    double m1 = sum / Nall;
    double var1 = sumsq / Nall - m1 * m1;
    double scaled = (double)g1[0] / sqrt(var1 + 1e-5);
    if (tid == 0) { bn1[0] = (float)m1; bn1[1] = (float)scaled; }
    const double Rinv = 1.0 / (double)ROWSX;
    if (tid < 64) xbarn[tid] = (float)((S1d[tid] * Rinv - m1) * scaled) + be1[0];
#pragma unroll
    for (int e = 0; e < 16; ++e) {
        int idx = tid * 16 + e;
        int a = idx >> 6, b = idx & 63;
        double cov = S2d[idx] * Rinv - (S1d[a] * Rinv) * (S1d[b] * Rinv);
        covn[idx] = (float)(cov * scaled * scaled);
    }
}

// ---------------- K5: analytic BN2 stats per feature -----------------------
__global__ __launch_bounds__(64) void k_bn2(
        const float* __restrict__ covn, const float* __restrict__ xbarn,
        const float* __restrict__ W2, const float* __restrict__ b2,
        const float* __restrict__ g2, float* __restrict__ m2, float* __restrict__ t2) {
    int f = blockIdx.x;
    int j = threadIdx.x;
    float wj = W2[(size_t)f * 64 + j];
    float t1 = 0.f;
    for (int b = 0; b < 64; ++b) t1 += covn[j * 64 + b] * W2[(size_t)f * 64 + b];
    float vc = wj * t1;
    float mc = wj * xbarn[j];
#pragma unroll
    for (int off = 32; off; off >>= 1) {
        vc += __shfl_down(vc, off);
        mc += __shfl_down(mc, off);
    }
    if (j == 0) {
        m2[f] = mc + b2[f];
        t2[f] = g2[f] * rsqrtf(vc + 1e-5f);
    }
}

// ---------------- K6: fused BN1-apply + GEMM2 + BN2 + relu + W3 dot --------
__global__ __launch_bounds__(256) void k_mlp(
        const float* __restrict__ xbuf, const float* __restrict__ bn1,
        const float* __restrict__ be1,
        const float* __restrict__ W2, const float* __restrict__ m2,
        const float* __restrict__ t2, const float* __restrict__ be2,
        const float* __restrict__ W3, const float* __restrict__ b3,
        float* __restrict__ z) {
    __shared__ float Xs[64][68];
    __shared__ float Ws[64][68];
    __shared__ float mcs[64], tcs[64], becs[64], w3s[64];
    __shared__ float part[16][64];
    int tid = threadIdx.x;
    int r0 = blockIdx.x * 64;
    float m1 = bn1[0], sc = bn1[1], sh = be1[0];
    int lr = tid >> 2, lq = tid & 3;
    {
        const float* Xb = xbuf + (size_t)(r0 + lr) * 64;
#pragma unroll
        for (int u = 0; u < 4; ++u) {
            int c = (lq + 4 * u) * 4;
            float4 xv = *reinterpret_cast<const float4*>(&Xb[c]);
            xv.x = (xv.x - m1) * sc + sh;
            xv.y = (xv.y - m1) * sc + sh;
            xv.z = (xv.z - m1) * sc + sh;
            xv.w = (xv.w - m1) * sc + sh;
            *reinterpret_cast<float4*>(&Xs[lr][c]) = xv;
        }
    }
    int tx = tid & 15, ty = tid >> 4;
    float zacc[4] = {};
    for (int fc = 0; fc < FF; fc += 64) {
        const float* Wb = W2 + (size_t)(fc + lr) * 64;
#pragma unroll
        for (int u = 0; u < 4; ++u) {
            int c = (lq + 4 * u) * 4;
            *reinterpret_cast<float4*>(&Ws[lr][c]) = *reinterpret_cast<const float4*>(&Wb[c]);
        }
        if (tid < 64) {
            mcs[tid] = m2[fc + tid]; tcs[tid] = t2[fc + tid];
            becs[tid] = be2[fc + tid]; w3s[tid] = W3[fc + tid];
        }
        __syncthreads();
        float acc[4][4] = {};
#pragma unroll
        for (int k4 = 0; k4 < 16; ++k4) {
            float4 a[4], b[4];
#pragma unroll
            for (int i = 0; i < 4; ++i) a[i] = *reinterpret_cast<const float4*>(&Xs[ty + 16 * i][k4 * 4]);
#pragma unroll
            for (int j = 0; j < 4; ++j) b[j] = *reinterpret_cast<const float4*>(&Ws[tx + 16 * j][k4 * 4]);
#pragma unroll
            for (int i = 0; i < 4; ++i)
#pragma unroll
                for (int j = 0; j < 4; ++j)
                    acc[i][j] += a[i].x * b[j].x + a[i].y * b[j].y
                               + a[i].z * b[j].z + a[i].w * b[j].w;
        }
#pragma unroll
        for (int j = 0; j < 4; ++j) {
            int f = tx + 16 * j;
            float mcf = mcs[f], tcf = tcs[f], bef = becs[f], w3f = w3s[f];
#pragma unroll
            for (int i = 0; i < 4; ++i) {
                float yb = (acc[i][j] - mcf) * tcf + bef;
                zacc[i] += fmaxf(yb, 0.f) * w3f;
            }
        }
        __syncthreads();
    }
#pragma unroll
    for (int i = 0; i < 4; ++i) part[tx][ty + 16 * i] = zacc[i];
    __syncthreads();
    if (tid < 64) {
        float s = 0.f;
#pragma unroll
        for (int e = 0; e < 16; ++e) s += part[e][tid];
        z[r0 + tid] = s + b3[0];
    }
}

// ---------------- K7: pair-sum + BN3 stats ---------------------------------
__global__ __launch_bounds__(256) void k_pair(const float* __restrict__ z,
        float* __restrict__ v, double* __restrict__ sums3) {
    int i = blockIdx.x * 256 + threadIdx.x;
    float val = z[2 * i] + z[2 * i + 1];
    v[i] = val;
    float s = val, ss = val * val;
#pragma unroll
    for (int off = 32; off; off >>= 1) {
        s += __shfl_down(s, off);
        ss += __shfl_down(ss, off);
    }
    __shared__ float bs[4], bss[4];
    int lane = threadIdx.x & 63, w = threadIdx.x >> 6;
    if (lane == 0) { bs[w] = s; bss[w] = ss; }
    __syncthreads();
    if (threadIdx.x == 0) {
        atomicAdd(&sums3[0], (double)(bs[0] + bs[1] + bs[2] + bs[3]));
        atomicAdd(&sums3[1], (double)(bss[0] + bss[1] + bss[2] + bss[3]));
    }
}

// ---------------- K8: finalize BN3 -----------------------------------------
__global__ void k_fin3(const double* __restrict__ sums3, const float* __restrict__ g3,
                       float* __restrict__ bn3) {
    double m = sums3[0] / (double)PAIRS;
    double var = sums3[1] / (double)PAIRS - m * m;
    bn3[0] = (float)m;
    bn3[1] = (float)((double)g3[0] / sqrt(var + 1e-5));
}

// ---------------- K9: write output -----------------------------------------
__global__ void k_out(const float* __restrict__ v, const float* __restrict__ bn3,
                      const float* __restrict__ be3, float* __restrict__ out) {
    int i = blockIdx.x * 256 + threadIdx.x;
    if (i < PAIRS) out[i] = (v[i] - bn3[0]) * bn3[1] + be3[0];
}

extern "C" void kernel_launch(void* const* d_in, const int* in_sizes, int n_in,
                              void* d_out, int out_size, void* d_ws, size_t ws_size,
                              hipStream_t stream) {
    (void)in_sizes; (void)n_in; (void)out_size; (void)ws_size;
    const float* tgt = (const float*)d_in[0];
    const float* mem = (const float*)d_in[1];
    const float* W1  = (const float*)d_in[2];
    const float* b1  = (const float*)d_in[3];
    const float* se  = (const float*)d_in[4];
    const float* W2  = (const float*)d_in[5];
    const float* b2  = (const float*)d_in[6];
    const float* W3  = (const float*)d_in[7];
    const float* b3  = (const float*)d_in[8];
    const float* g1  = (const float*)d_in[9];
    const float* be1 = (const float*)d_in[10];
    const float* g2  = (const float*)d_in[11];
    const float* be2 = (const float*)d_in[12];
    const float* g3  = (const float*)d_in[13];
    const float* be3 = (const float*)d_in[14];
    const int*  flag = (const int*)d_in[15];
    float* out = (float*)d_out;

    char* ws = (char*)d_ws;
    size_t off = 0;
    auto alloc = [&](size_t bytes) -> void* {
        void* p = ws + off;
        off = (off + bytes + 255) & ~(size_t)255;
        return p;
    };
    float* sig   = (float*)alloc((size_t)SSZ * SSZ * 4);
    __hip_bfloat16* QKb = (__hip_bfloat16*)alloc((size_t)(NQ + NK) * SSZ * D * 2); // 21 MB
    float* xbuf  = (float*)alloc((size_t)ROWSX * 64 * 4);            // 8 MB
    float* z     = (float*)alloc((size_t)ROWSX * 4);
    float* v     = (float*)alloc((size_t)PAIRS * 4);
    float* m2    = (float*)alloc((size_t)FF * 4);
    float* t2    = (float*)alloc((size_t)FF * 4);
    float* xbarn = (float*)alloc(64 * 4);
    float* covn  = (float*)alloc(64 * 64 * 4);
    float* bn1   = (float*)alloc(16);
    float* bn3   = (float*)alloc(16);
    size_t statsStart = off;
    double* S1d   = (double*)alloc(64 * 8);
    double* S2d   = (double*)alloc(64 * 64 * 8);
    double* sums3 = (double*)alloc(2 * 8);
    size_t statsEnd = off;

    hipMemsetAsync(ws + statsStart, 0, statsEnd - statsStart, stream);

    k_sig<<<16, 256, 0, stream>>>(se, flag, sig);
    k_gemm1<<<((NQ + NK) * SSZ / 64) * (D / 64), 256, 0, stream>>>(tgt, mem, W1, b1, flag, QKb);
    k_score_mfma<<<NQ * (NK / 4), 256, 0, stream>>>(QKb, sig, xbuf);
    k_stats1<<<64, 256, 0, stream>>>(xbuf, S1d, S2d);
    k_fin1<<<1, 256, 0, stream>>>(S1d, S2d, g1, be1, bn1, xbarn, covn);
    k_bn2<<<FF, 64, 0, stream>>>(covn, xbarn, W2, b2, g2, m2, t2);
    k_mlp<<<ROWSX / 64, 256, 0, stream>>>(xbuf, bn1, be1, W2, m2, t2, be2, W3, b3, z);
    k_pair<<<PAIRS / 256, 256, 0, stream>>>(z, v, sums3);
    k_fin3<<<1, 1, 0, stream>>>(sums3, g3, bn3);
    k_out<<<PAIRS / 256, 256, 0, stream>>>(v, bn3, be3, out);
}

// Round 3
// 520.859 us; speedup vs baseline: 5.0189x; 1.4825x over previous
//
#include <hip/hip_runtime.h>
#include <hip/hip_bf16.h>
#include <math.h>
#include <float.h>

// dims
constexpr int NQ = 64, NK = 256, SSZ = 64, D = 512, FF = 2048;
constexpr int PAIRS = NQ * NK;          // 16384
constexpr int ROWSX = 2 * PAIRS;        // 32768
constexpr int NX = (NQ + NK) * SSZ;     // 20480 rows of X = [tgt;mem]

typedef __bf16 bf16x8 __attribute__((ext_vector_type(8)));
typedef float floatx16 __attribute__((ext_vector_type(16)));

// ---------------- K0: sigmoid of score_embed (or 1.0 if !flag) -------------
__global__ void k_sig(const float* __restrict__ se, const int* __restrict__ flag,
                      float* __restrict__ sig) {
    int i = blockIdx.x * blockDim.x + threadIdx.x;
    if (i < SSZ * SSZ) {
        sig[i] = (*flag) ? 1.0f / (1.0f + expf(-se[i])) : 1.0f;
    }
}

// ---------------- K0b: convert X=[tgt;mem] and W1 to bf16 ------------------
__global__ __launch_bounds__(256) void k_cvt(
        const float* __restrict__ tgt, const float* __restrict__ mem,
        const float* __restrict__ W1,
        __hip_bfloat16* __restrict__ Xb, __hip_bfloat16* __restrict__ W1b) {
    constexpr int T4 = NQ * SSZ * D / 4;   // tgt float4 count   524288
    constexpr int X4 = NX * D / 4;         // X float4 count    2621440
    constexpr int W4 = D * D / 4;          // W1 float4 count     65536
    int idx = blockIdx.x * 256 + threadIdx.x;
    if (idx >= X4 + W4) return;
    const float* src;
    __hip_bfloat16* dst;
    if (idx < T4)      { src = tgt + (size_t)idx * 4;        dst = Xb + (size_t)idx * 4; }
    else if (idx < X4) { src = mem + (size_t)(idx - T4) * 4; dst = Xb + (size_t)idx * 4; }
    else               { src = W1 + (size_t)(idx - X4) * 4;  dst = W1b + (size_t)(idx - X4) * 4; }
    float4 v = *reinterpret_cast<const float4*>(src);
    union { __hip_bfloat16 h[4]; uint2 u; } o;
    o.h[0] = __float2bfloat16(v.x); o.h[1] = __float2bfloat16(v.y);
    o.h[2] = __float2bfloat16(v.z); o.h[3] = __float2bfloat16(v.w);
    *reinterpret_cast<uint2*>(dst) = o.u;
}

// ---------------- K1: MFMA GEMM1: C = Xb @ W1b^T + b1 (bf16 out) -----------
// 128x128 tile per block, 4 waves of 64x64 (2x2 quadrants of 32x32x16).
// If !flag: C tile = Xb tile (identity path).
__global__ __launch_bounds__(256, 2) void k_gemm1_mfma(
        const __hip_bfloat16* __restrict__ Xb, const __hip_bfloat16* __restrict__ W1b,
        const float* __restrict__ b1, const int* __restrict__ flag,
        __hip_bfloat16* __restrict__ C) {
    constexpr int LDR = 72;  // padded row: 72 bf16 = 144 B (16B-aligned rows)
    __shared__ __attribute__((aligned(16))) unsigned short lds[2 * 128 * LDR]; // 36864 B
    unsigned short* As = lds;
    unsigned short* Bs = lds + 128 * LDR;
    const unsigned short* Xu = reinterpret_cast<const unsigned short*>(Xb);
    const unsigned short* Wu = reinterpret_cast<const unsigned short*>(W1b);
    unsigned short* Cu = reinterpret_cast<unsigned short*>(C);

    int tid = threadIdx.x;
    int bm = blockIdx.x >> 2, bn = blockIdx.x & 3;
    int m0 = bm * 128, n0 = bn * 128;

    if (!(*flag)) {
        // identity: copy Xb tile into C tile
#pragma unroll
        for (int i = 0; i < 8; ++i) {
            int id = i * 256 + tid;
            int row = id >> 4, ch = id & 15;
            uint4 v = *reinterpret_cast<const uint4*>(Xu + (size_t)(m0 + row) * D + n0 + ch * 8);
            *reinterpret_cast<uint4*>(Cu + (size_t)(m0 + row) * D + n0 + ch * 8) = v;
        }
        return;
    }

    int w = tid >> 6, l = tid & 63, h = l >> 5, c = l & 31;
    int wm = w >> 1, wn = w & 1;
    floatx16 acc00 = {}, acc01 = {}, acc10 = {}, acc11 = {};

    for (int kb = 0; kb < D; kb += 64) {
#pragma unroll
        for (int i = 0; i < 4; ++i) {
            int id = i * 256 + tid;        // 0..1023
            int row = id >> 3, c8 = id & 7;
            uint4 va = *reinterpret_cast<const uint4*>(Xu + (size_t)(m0 + row) * D + kb + c8 * 8);
            *reinterpret_cast<uint4*>(&As[row * LDR + c8 * 8]) = va;
            uint4 vb = *reinterpret_cast<const uint4*>(Wu + (size_t)(n0 + row) * D + kb + c8 * 8);
            *reinterpret_cast<uint4*>(&Bs[row * LDR + c8 * 8]) = vb;
        }
        __syncthreads();
        const unsigned short* pA = As + (wm * 64) * LDR;
        const unsigned short* pB = Bs + (wn * 64) * LDR;
#pragma unroll
        for (int st = 0; st < 4; ++st) {
            int d = st * 16 + h * 8;
            bf16x8 a0 = *reinterpret_cast<const bf16x8*>(pA + c * LDR + d);
            bf16x8 a1 = *reinterpret_cast<const bf16x8*>(pA + (32 + c) * LDR + d);
            bf16x8 b0 = *reinterpret_cast<const bf16x8*>(pB + c * LDR + d);
            bf16x8 b1 = *reinterpret_cast<const bf16x8*>(pB + (32 + c) * LDR + d);
            acc00 = __builtin_amdgcn_mfma_f32_32x32x16_bf16(a0, b0, acc00, 0, 0, 0);
            acc01 = __builtin_amdgcn_mfma_f32_32x32x16_bf16(a0, b1, acc01, 0, 0, 0);
            acc10 = __builtin_amdgcn_mfma_f32_32x32x16_bf16(a1, b0, acc10, 0, 0, 0);
            acc11 = __builtin_amdgcn_mfma_f32_32x32x16_bf16(a1, b1, acc11, 0, 0, 0);
        }
        __syncthreads();
    }

    // epilogue: row(m') = (r&3)+8*(r>>2)+4*h, col(n') = c
    int mbase = m0 + wm * 64, nbase = n0 + wn * 64;
    float bia0 = b1[nbase + c], bia1 = b1[nbase + 32 + c];
#pragma unroll
    for (int mi = 0; mi < 2; ++mi) {
        const floatx16& A0 = mi ? acc10 : acc00;
        const floatx16& A1 = mi ? acc11 : acc01;
#pragma unroll
        for (int r = 0; r < 16; ++r) {
            int m = mbase + mi * 32 + (r & 3) + 8 * (r >> 2) + 4 * h;
            C[(size_t)m * D + nbase + c] = __float2bfloat16(A0[r] + bia0);
            C[(size_t)m * D + nbase + 32 + c] = __float2bfloat16(A1[r] + bia1);
        }
    }
}

// ---------------- K2: MFMA score einsum + sigmoid + dual max ---------------
// block = 4 waves; wave w handles pair p = qi*256 + (kg*4+w).
__global__ __launch_bounds__(256, 2) void k_score_mfma(
        const __hip_bfloat16* __restrict__ QKb, const float* __restrict__ sig,
        float* __restrict__ xbuf) {
    constexpr int LDR = 72;
    __shared__ __attribute__((aligned(16))) unsigned short lds[5 * 64 * LDR]; // 46080 B
    const unsigned short* QKu = reinterpret_cast<const unsigned short*>(QKb);

    int tid = threadIdx.x;
    int w = tid >> 6;
    int l = tid & 63;
    int h = l >> 5;
    int c = l & 31;

    int qi = blockIdx.x >> 6;
    int kg = blockIdx.x & 63;

    floatx16 acc00 = {}, acc01 = {}, acc10 = {}, acc11 = {};

    for (int kb = 0; kb < D; kb += 64) {
#pragma unroll
        for (int i = 0; i < 10; ++i) {
            int slot = i * 256 + tid;
            int tile = slot >> 9;
            int s512 = slot & 511;
            int row = s512 >> 3, c8 = s512 & 7;
            int grow = (tile == 0) ? (qi * 64 + row)
                                   : (NQ * SSZ + (kg * 4 + tile - 1) * 64 + row);
            uint4 v = *reinterpret_cast<const uint4*>(QKu + (size_t)grow * D + kb + c8 * 8);
            *reinterpret_cast<uint4*>(&lds[(tile * 64 + row) * LDR + c8 * 8]) = v;
        }
        __syncthreads();
        const unsigned short* ldsQ = &lds[0];
        const unsigned short* ldsK = &lds[(1 + w) * 64 * LDR];
#pragma unroll
        for (int st = 0; st < 4; ++st) {
            int d = st * 16 + h * 8;
            bf16x8 a0 = *reinterpret_cast<const bf16x8*>(ldsK + (c) * LDR + d);
            bf16x8 a1 = *reinterpret_cast<const bf16x8*>(ldsK + (32 + c) * LDR + d);
            bf16x8 b0 = *reinterpret_cast<const bf16x8*>(ldsQ + (c) * LDR + d);
            bf16x8 b1 = *reinterpret_cast<const bf16x8*>(ldsQ + (32 + c) * LDR + d);
            acc00 = __builtin_amdgcn_mfma_f32_32x32x16_bf16(a0, b0, acc00, 0, 0, 0);
            acc01 = __builtin_amdgcn_mfma_f32_32x32x16_bf16(a0, b1, acc01, 0, 0, 0);
            acc10 = __builtin_amdgcn_mfma_f32_32x32x16_bf16(a1, b0, acc10, 0, 0, 0);
            acc11 = __builtin_amdgcn_mfma_f32_32x32x16_bf16(a1, b1, acc11, 0, 0, 0);
        }
        __syncthreads();
    }

    float* sigl = reinterpret_cast<float*>(lds);
#pragma unroll
    for (int i = 0; i < 4; ++i) {
        int idx = i * 256 + tid;
        *reinterpret_cast<float4*>(sigl + idx * 4) =
            *reinterpret_cast<const float4*>(sig + idx * 4);
    }
    __syncthreads();

    int p = qi * 256 + kg * 4 + w;
    float tmax0 = -FLT_MAX, tmax1 = -FLT_MAX;
    float smax[2][16];
#pragma unroll
    for (int si = 0; si < 2; ++si) {
        const floatx16& A0 = si ? acc10 : acc00;
        const floatx16& A1 = si ? acc11 : acc01;
#pragma unroll
        for (int r = 0; r < 16; ++r) {
            int srow = si * 32 + (r & 3) + 8 * (r >> 2) + 4 * h;
            float v0 = A0[r] * sigl[srow * 64 + c];
            float v1 = A1[r] * sigl[srow * 64 + 32 + c];
            tmax0 = fmaxf(tmax0, v0);
            tmax1 = fmaxf(tmax1, v1);
            smax[si][r] = fmaxf(v0, v1);
        }
    }
    tmax0 = fmaxf(tmax0, __shfl_xor(tmax0, 32, 64));
    tmax1 = fmaxf(tmax1, __shfl_xor(tmax1, 32, 64));
    if (h == 0) {
        xbuf[(size_t)(2 * p) * 64 + c] = tmax0;
        xbuf[(size_t)(2 * p) * 64 + 32 + c] = tmax1;
    }
#pragma unroll
    for (int stage = 1; stage < 32; stage <<= 1) {
#pragma unroll
        for (int si = 0; si < 2; ++si)
#pragma unroll
            for (int r = 0; r < 16; ++r)
                smax[si][r] = fmaxf(smax[si][r], __shfl_xor(smax[si][r], stage, 64));
    }
    if (c == 0) {
#pragma unroll
        for (int si = 0; si < 2; ++si)
#pragma unroll
            for (int r = 0; r < 16; ++r) {
                int srow = si * 32 + (r & 3) + 8 * (r >> 2) + 4 * h;
                xbuf[(size_t)(2 * p + 1) * 64 + srow] = smax[si][r];
            }
    }
}

// ---------------- K3: row stats S1[64], S2[64][64] over xbuf ---------------
__global__ __launch_bounds__(256) void k_stats1(const float* __restrict__ xbuf,
        double* __restrict__ S1d, double* __restrict__ S2d) {
    __shared__ float xr[4][64];
    int tid = threadIdx.x;
    int row0 = blockIdx.x * 512;
    float acc[16] = {};
    float s1 = 0.f;
    int pbase = tid * 16;
    for (int it = 0; it < 128; ++it) {
        int r = row0 + it * 4;
        xr[tid >> 6][tid & 63] = xbuf[(size_t)(r + (tid >> 6)) * 64 + (tid & 63)];
        __syncthreads();
#pragma unroll
        for (int e = 0; e < 16; ++e) {
            int a = (pbase + e) >> 6, b = (pbase + e) & 63;
            acc[e] += xr[0][a] * xr[0][b] + xr[1][a] * xr[1][b]
                    + xr[2][a] * xr[2][b] + xr[3][a] * xr[3][b];
        }
        if (tid < 64) s1 += xr[0][tid] + xr[1][tid] + xr[2][tid] + xr[3][tid];
        __syncthreads();
    }
#pragma unroll
    for (int e = 0; e < 16; ++e) atomicAdd(&S2d[pbase + e], (double)acc[e]);
    if (tid < 64) atomicAdd(&S1d[tid], (double)s1);
}

// ---------------- K4: finalize BN1 + normalized mean/cov -------------------
__global__ __launch_bounds__(256) void k_fin1(
        const double* __restrict__ S1d, const double* __restrict__ S2d,
        const float* __restrict__ g1, const float* __restrict__ be1,
        float* __restrict__ bn1, float* __restrict__ xbarn, float* __restrict__ covn) {
    int tid = threadIdx.x;
    double sum = 0.0, sumsq = 0.0;
    for (int j = 0; j < 64; ++j) { sum += S1d[j]; sumsq += S2d[j * 64 + j]; }
    const double Nall = (double)ROWSX * 64.0;
    double m1 = sum / Nall;
    double var1 = sumsq / Nall - m1 * m1;
    double scaled = (double)g1[0] / sqrt(var1 + 1e-5);
    if (tid == 0) { bn1[0] = (float)m1; bn1[1] = (float)scaled; }
    const double Rinv = 1.0 / (double)ROWSX;
    if (tid < 64) xbarn[tid] = (float)((S1d[tid] * Rinv - m1) * scaled) + be1[0];
#pragma unroll
    for (int e = 0; e < 16; ++e) {
        int idx = tid * 16 + e;
        int a = idx >> 6, b = idx & 63;
        double cov = S2d[idx] * Rinv - (S1d[a] * Rinv) * (S1d[b] * Rinv);
        covn[idx] = (float)(cov * scaled * scaled);
    }
}

// ---------------- K5: analytic BN2 stats per feature -----------------------
__global__ __launch_bounds__(64) void k_bn2(
        const float* __restrict__ covn, const float* __restrict__ xbarn,
        const float* __restrict__ W2, const float* __restrict__ b2,
        const float* __restrict__ g2, float* __restrict__ m2, float* __restrict__ t2) {
    int f = blockIdx.x;
    int j = threadIdx.x;
    float wj = W2[(size_t)f * 64 + j];
    float t1 = 0.f;
    for (int b = 0; b < 64; ++b) t1 += covn[j * 64 + b] * W2[(size_t)f * 64 + b];
    float vc = wj * t1;
    float mc = wj * xbarn[j];
#pragma unroll
    for (int off = 32; off; off >>= 1) {
        vc += __shfl_down(vc, off);
        mc += __shfl_down(mc, off);
    }
    if (j == 0) {
        m2[f] = mc + b2[f];
        t2[f] = g2[f] * rsqrtf(vc + 1e-5f);
    }
}

// ---------------- K6: fused BN1-apply + GEMM2 + BN2 + relu + W3 dot --------
__global__ __launch_bounds__(256) void k_mlp(
        const float* __restrict__ xbuf, const float* __restrict__ bn1,
        const float* __restrict__ be1,
        const float* __restrict__ W2, const float* __restrict__ m2,
        const float* __restrict__ t2, const float* __restrict__ be2,
        const float* __restrict__ W3, const float* __restrict__ b3,
        float* __restrict__ z) {
    __shared__ float Xs[64][68];
    __shared__ float Ws[64][68];
    __shared__ float mcs[64], tcs[64], becs[64], w3s[64];
    __shared__ float part[16][64];
    int tid = threadIdx.x;
    int r0 = blockIdx.x * 64;
    float m1 = bn1[0], sc = bn1[1], sh = be1[0];
    int lr = tid >> 2, lq = tid & 3;
    {
        const float* Xb = xbuf + (size_t)(r0 + lr) * 64;
#pragma unroll
        for (int u = 0; u < 4; ++u) {
            int c = (lq + 4 * u) * 4;
            float4 xv = *reinterpret_cast<const float4*>(&Xb[c]);
            xv.x = (xv.x - m1) * sc + sh;
            xv.y = (xv.y - m1) * sc + sh;
            xv.z = (xv.z - m1) * sc + sh;
            xv.w = (xv.w - m1) * sc + sh;
            *reinterpret_cast<float4*>(&Xs[lr][c]) = xv;
        }
    }
    int tx = tid & 15, ty = tid >> 4;
    float zacc[4] = {};
    for (int fc = 0; fc < FF; fc += 64) {
        const float* Wb = W2 + (size_t)(fc + lr) * 64;
#pragma unroll
        for (int u = 0; u < 4; ++u) {
            int c = (lq + 4 * u) * 4;
            *reinterpret_cast<float4*>(&Ws[lr][c]) = *reinterpret_cast<const float4*>(&Wb[c]);
        }
        if (tid < 64) {
            mcs[tid] = m2[fc + tid]; tcs[tid] = t2[fc + tid];
            becs[tid] = be2[fc + tid]; w3s[tid] = W3[fc + tid];
        }
        __syncthreads();
        float acc[4][4] = {};
#pragma unroll
        for (int k4 = 0; k4 < 16; ++k4) {
            float4 a[4], b[4];
#pragma unroll
            for (int i = 0; i < 4; ++i) a[i] = *reinterpret_cast<const float4*>(&Xs[ty + 16 * i][k4 * 4]);
#pragma unroll
            for (int j = 0; j < 4; ++j) b[j] = *reinterpret_cast<const float4*>(&Ws[tx + 16 * j][k4 * 4]);
#pragma unroll
            for (int i = 0; i < 4; ++i)
#pragma unroll
                for (int j = 0; j < 4; ++j)
                    acc[i][j] += a[i].x * b[j].x + a[i].y * b[j].y
                               + a[i].z * b[j].z + a[i].w * b[j].w;
        }
#pragma unroll
        for (int j = 0; j < 4; ++j) {
            int f = tx + 16 * j;
            float mcf = mcs[f], tcf = tcs[f], bef = becs[f], w3f = w3s[f];
#pragma unroll
            for (int i = 0; i < 4; ++i) {
                float yb = (acc[i][j] - mcf) * tcf + bef;
                zacc[i] += fmaxf(yb, 0.f) * w3f;
            }
        }
        __syncthreads();
    }
#pragma unroll
    for (int i = 0; i < 4; ++i) part[tx][ty + 16 * i] = zacc[i];
    __syncthreads();
    if (tid < 64) {
        float s = 0.f;
#pragma unroll
        for (int e = 0; e < 16; ++e) s += part[e][tid];
        z[r0 + tid] = s + b3[0];
    }
}

// ---------------- K7: pair-sum + BN3 stats ---------------------------------
__global__ __launch_bounds__(256) void k_pair(const float* __restrict__ z,
        float* __restrict__ v, double* __restrict__ sums3) {
    int i = blockIdx.x * 256 + threadIdx.x;
    float val = z[2 * i] + z[2 * i + 1];
    v[i] = val;
    float s = val, ss = val * val;
#pragma unroll
    for (int off = 32; off; off >>= 1) {
        s += __shfl_down(s, off);
        ss += __shfl_down(ss, off);
    }
    __shared__ float bs[4], bss[4];
    int lane = threadIdx.x & 63, w = threadIdx.x >> 6;
    if (lane == 0) { bs[w] = s; bss[w] = ss; }
    __syncthreads();
    if (threadIdx.x == 0) {
        atomicAdd(&sums3[0], (double)(bs[0] + bs[1] + bs[2] + bs[3]));
        atomicAdd(&sums3[1], (double)(bss[0] + bss[1] + bss[2] + bss[3]));
    }
}

// ---------------- K8: finalize BN3 -----------------------------------------
__global__ void k_fin3(const double* __restrict__ sums3, const float* __restrict__ g3,
                       float* __restrict__ bn3) {
    double m = sums3[0] / (double)PAIRS;
    double var = sums3[1] / (double)PAIRS - m * m;
    bn3[0] = (float)m;
    bn3[1] = (float)((double)g3[0] / sqrt(var + 1e-5));
}

// ---------------- K9: write output -----------------------------------------
__global__ void k_out(const float* __restrict__ v, const float* __restrict__ bn3,
                      const float* __restrict__ be3, float* __restrict__ out) {
    int i = blockIdx.x * 256 + threadIdx.x;
    if (i < PAIRS) out[i] = (v[i] - bn3[0]) * bn3[1] + be3[0];
}

extern "C" void kernel_launch(void* const* d_in, const int* in_sizes, int n_in,
                              void* d_out, int out_size, void* d_ws, size_t ws_size,
                              hipStream_t stream) {
    (void)in_sizes; (void)n_in; (void)out_size; (void)ws_size;
    const float* tgt = (const float*)d_in[0];
    const float* mem = (const float*)d_in[1];
    const float* W1  = (const float*)d_in[2];
    const float* b1  = (const float*)d_in[3];
    const float* se  = (const float*)d_in[4];
    const float* W2  = (const float*)d_in[5];
    const float* b2  = (const float*)d_in[6];
    const float* W3  = (const float*)d_in[7];
    const float* b3  = (const float*)d_in[8];
    const float* g1  = (const float*)d_in[9];
    const float* be1 = (const float*)d_in[10];
    const float* g2  = (const float*)d_in[11];
    const float* be2 = (const float*)d_in[12];
    const float* g3  = (const float*)d_in[13];
    const float* be3 = (const float*)d_in[14];
    const int*  flag = (const int*)d_in[15];
    float* out = (float*)d_out;

    char* ws = (char*)d_ws;
    size_t off = 0;
    auto alloc = [&](size_t bytes) -> void* {
        void* p = ws + off;
        off = (off + bytes + 255) & ~(size_t)255;
        return p;
    };
    float* sig   = (float*)alloc((size_t)SSZ * SSZ * 4);
    __hip_bfloat16* Xb  = (__hip_bfloat16*)alloc((size_t)NX * D * 2);   // 21 MB
    __hip_bfloat16* W1b = (__hip_bfloat16*)alloc((size_t)D * D * 2);    // 0.5 MB
    __hip_bfloat16* QKb = (__hip_bfloat16*)alloc((size_t)NX * D * 2);   // 21 MB
    float* xbuf  = (float*)alloc((size_t)ROWSX * 64 * 4);               // 8 MB
    float* z     = (float*)alloc((size_t)ROWSX * 4);
    float* v     = (float*)alloc((size_t)PAIRS * 4);
    float* m2    = (float*)alloc((size_t)FF * 4);
    float* t2    = (float*)alloc((size_t)FF * 4);
    float* xbarn = (float*)alloc(64 * 4);
    float* covn  = (float*)alloc(64 * 64 * 4);
    float* bn1   = (float*)alloc(16);
    float* bn3   = (float*)alloc(16);
    size_t statsStart = off;
    double* S1d   = (double*)alloc(64 * 8);
    double* S2d   = (double*)alloc(64 * 64 * 8);
    double* sums3 = (double*)alloc(2 * 8);
    size_t statsEnd = off;

    hipMemsetAsync(ws + statsStart, 0, statsEnd - statsStart, stream);

    k_sig<<<16, 256, 0, stream>>>(se, flag, sig);
    constexpr int CVT4 = (NX * D + D * D) / 4;
    k_cvt<<<(CVT4 + 255) / 256, 256, 0, stream>>>(tgt, mem, W1, Xb, W1b);
    k_gemm1_mfma<<<(NX / 128) * (D / 128), 256, 0, stream>>>(Xb, W1b, b1, flag, QKb);
    k_score_mfma<<<NQ * (NK / 4), 256, 0, stream>>>(QKb, sig, xbuf);
    k_stats1<<<64, 256, 0, stream>>>(xbuf, S1d, S2d);
    k_fin1<<<1, 256, 0, stream>>>(S1d, S2d, g1, be1, bn1, xbarn, covn);
    k_bn2<<<FF, 64, 0, stream>>>(covn, xbarn, W2, b2, g2, m2, t2);
    k_mlp<<<ROWSX / 64, 256, 0, stream>>>(xbuf, bn1, be1, W2, m2, t2, be2, W3, b3, z);
    k_pair<<<PAIRS / 256, 256, 0, stream>>>(z, v, sums3);
    k_fin3<<<1, 1, 0, stream>>>(sums3, g3, bn3);
    k_out<<<PAIRS / 256, 256, 0, stream>>>(v, bn3, be3, out);
}

// Round 4
// 367.911 us; speedup vs baseline: 7.1053x; 1.4157x over previous
//
#include <hip/hip_runtime.h>
#include <hip/hip_bf16.h>
#include <math.h>
#include <float.h>

// dims
constexpr int NQ = 64, NK = 256, SSZ = 64, D = 512, FF = 2048;
constexpr int PAIRS = NQ * NK;          // 16384
constexpr int ROWSX = 2 * PAIRS;        // 32768
constexpr int NX = (NQ + NK) * SSZ;     // 20480 rows of X = [tgt;mem]

typedef __bf16 bf16x8 __attribute__((ext_vector_type(8)));
typedef float floatx16 __attribute__((ext_vector_type(16)));

// ---------------- K0: sigmoid of score_embed (or 1.0 if !flag) -------------
__global__ void k_sig(const float* __restrict__ se, const int* __restrict__ flag,
                      float* __restrict__ sig) {
    int i = blockIdx.x * blockDim.x + threadIdx.x;
    if (i < SSZ * SSZ) {
        sig[i] = (*flag) ? 1.0f / (1.0f + expf(-se[i])) : 1.0f;
    }
}

// ---------------- K0b: convert X=[tgt;mem], W1, W2 to bf16 -----------------
__global__ __launch_bounds__(256) void k_cvt(
        const float* __restrict__ tgt, const float* __restrict__ mem,
        const float* __restrict__ W1, const float* __restrict__ W2,
        __hip_bfloat16* __restrict__ Xb, __hip_bfloat16* __restrict__ W1b,
        __hip_bfloat16* __restrict__ W2b) {
    constexpr int T4 = NQ * SSZ * D / 4;   // tgt float4 count
    constexpr int X4 = NX * D / 4;         // X float4 count
    constexpr int W4 = D * D / 4;          // W1 float4 count
    constexpr int V4 = FF * 64 / 4;        // W2 float4 count
    int idx = blockIdx.x * 256 + threadIdx.x;
    if (idx >= X4 + W4 + V4) return;
    const float* src;
    __hip_bfloat16* dst;
    if (idx < T4)           { src = tgt + (size_t)idx * 4;             dst = Xb + (size_t)idx * 4; }
    else if (idx < X4)      { src = mem + (size_t)(idx - T4) * 4;      dst = Xb + (size_t)idx * 4; }
    else if (idx < X4 + W4) { src = W1 + (size_t)(idx - X4) * 4;       dst = W1b + (size_t)(idx - X4) * 4; }
    else                    { src = W2 + (size_t)(idx - X4 - W4) * 4;  dst = W2b + (size_t)(idx - X4 - W4) * 4; }
    float4 v = *reinterpret_cast<const float4*>(src);
    union { __hip_bfloat16 h[4]; uint2 u; } o;
    o.h[0] = __float2bfloat16(v.x); o.h[1] = __float2bfloat16(v.y);
    o.h[2] = __float2bfloat16(v.z); o.h[3] = __float2bfloat16(v.w);
    *reinterpret_cast<uint2*>(dst) = o.u;
}

// ---------------- K1: MFMA GEMM1: C = Xb @ W1b^T + b1 (bf16 out) -----------
__global__ __launch_bounds__(256, 2) void k_gemm1_mfma(
        const __hip_bfloat16* __restrict__ Xb, const __hip_bfloat16* __restrict__ W1b,
        const float* __restrict__ b1, const int* __restrict__ flag,
        __hip_bfloat16* __restrict__ C) {
    constexpr int LDR = 72;
    __shared__ __attribute__((aligned(16))) unsigned short lds[2 * 128 * LDR];
    unsigned short* As = lds;
    unsigned short* Bs = lds + 128 * LDR;
    const unsigned short* Xu = reinterpret_cast<const unsigned short*>(Xb);
    const unsigned short* Wu = reinterpret_cast<const unsigned short*>(W1b);
    unsigned short* Cu = reinterpret_cast<unsigned short*>(C);

    int tid = threadIdx.x;
    int bm = blockIdx.x >> 2, bn = blockIdx.x & 3;
    int m0 = bm * 128, n0 = bn * 128;

    if (!(*flag)) {
#pragma unroll
        for (int i = 0; i < 8; ++i) {
            int id = i * 256 + tid;
            int row = id >> 4, ch = id & 15;
            uint4 v = *reinterpret_cast<const uint4*>(Xu + (size_t)(m0 + row) * D + n0 + ch * 8);
            *reinterpret_cast<uint4*>(Cu + (size_t)(m0 + row) * D + n0 + ch * 8) = v;
        }
        return;
    }

    int w = tid >> 6, l = tid & 63, h = l >> 5, c = l & 31;
    int wm = w >> 1, wn = w & 1;
    floatx16 acc00 = {}, acc01 = {}, acc10 = {}, acc11 = {};

    for (int kb = 0; kb < D; kb += 64) {
#pragma unroll
        for (int i = 0; i < 4; ++i) {
            int id = i * 256 + tid;
            int row = id >> 3, c8 = id & 7;
            uint4 va = *reinterpret_cast<const uint4*>(Xu + (size_t)(m0 + row) * D + kb + c8 * 8);
            *reinterpret_cast<uint4*>(&As[row * LDR + c8 * 8]) = va;
            uint4 vb = *reinterpret_cast<const uint4*>(Wu + (size_t)(n0 + row) * D + kb + c8 * 8);
            *reinterpret_cast<uint4*>(&Bs[row * LDR + c8 * 8]) = vb;
        }
        __syncthreads();
        const unsigned short* pA = As + (wm * 64) * LDR;
        const unsigned short* pB = Bs + (wn * 64) * LDR;
#pragma unroll
        for (int st = 0; st < 4; ++st) {
            int d = st * 16 + h * 8;
            bf16x8 a0 = *reinterpret_cast<const bf16x8*>(pA + c * LDR + d);
            bf16x8 a1 = *reinterpret_cast<const bf16x8*>(pA + (32 + c) * LDR + d);
            bf16x8 b0 = *reinterpret_cast<const bf16x8*>(pB + c * LDR + d);
            bf16x8 b1 = *reinterpret_cast<const bf16x8*>(pB + (32 + c) * LDR + d);
            acc00 = __builtin_amdgcn_mfma_f32_32x32x16_bf16(a0, b0, acc00, 0, 0, 0);
            acc01 = __builtin_amdgcn_mfma_f32_32x32x16_bf16(a0, b1, acc01, 0, 0, 0);
            acc10 = __builtin_amdgcn_mfma_f32_32x32x16_bf16(a1, b0, acc10, 0, 0, 0);
            acc11 = __builtin_amdgcn_mfma_f32_32x32x16_bf16(a1, b1, acc11, 0, 0, 0);
        }
        __syncthreads();
    }

    int mbase = m0 + wm * 64, nbase = n0 + wn * 64;
    float bia0 = b1[nbase + c], bia1 = b1[nbase + 32 + c];
#pragma unroll
    for (int mi = 0; mi < 2; ++mi) {
        const floatx16& A0 = mi ? acc10 : acc00;
        const floatx16& A1 = mi ? acc11 : acc01;
#pragma unroll
        for (int r = 0; r < 16; ++r) {
            int m = mbase + mi * 32 + (r & 3) + 8 * (r >> 2) + 4 * h;
            C[(size_t)m * D + nbase + c] = __float2bfloat16(A0[r] + bia0);
            C[(size_t)m * D + nbase + 32 + c] = __float2bfloat16(A1[r] + bia1);
        }
    }
}

// ---------------- K2: MFMA score einsum + sigmoid + dual max ---------------
__global__ __launch_bounds__(256, 2) void k_score_mfma(
        const __hip_bfloat16* __restrict__ QKb, const float* __restrict__ sig,
        float* __restrict__ xbuf) {
    constexpr int LDR = 72;
    __shared__ __attribute__((aligned(16))) unsigned short lds[5 * 64 * LDR];
    const unsigned short* QKu = reinterpret_cast<const unsigned short*>(QKb);

    int tid = threadIdx.x;
    int w = tid >> 6;
    int l = tid & 63;
    int h = l >> 5;
    int c = l & 31;

    int qi = blockIdx.x >> 6;
    int kg = blockIdx.x & 63;

    floatx16 acc00 = {}, acc01 = {}, acc10 = {}, acc11 = {};

    for (int kb = 0; kb < D; kb += 64) {
#pragma unroll
        for (int i = 0; i < 10; ++i) {
            int slot = i * 256 + tid;
            int tile = slot >> 9;
            int s512 = slot & 511;
            int row = s512 >> 3, c8 = s512 & 7;
            int grow = (tile == 0) ? (qi * 64 + row)
                                   : (NQ * SSZ + (kg * 4 + tile - 1) * 64 + row);
            uint4 v = *reinterpret_cast<const uint4*>(QKu + (size_t)grow * D + kb + c8 * 8);
            *reinterpret_cast<uint4*>(&lds[(tile * 64 + row) * LDR + c8 * 8]) = v;
        }
        __syncthreads();
        const unsigned short* ldsQ = &lds[0];
        const unsigned short* ldsK = &lds[(1 + w) * 64 * LDR];
#pragma unroll
        for (int st = 0; st < 4; ++st) {
            int d = st * 16 + h * 8;
            bf16x8 a0 = *reinterpret_cast<const bf16x8*>(ldsK + (c) * LDR + d);
            bf16x8 a1 = *reinterpret_cast<const bf16x8*>(ldsK + (32 + c) * LDR + d);
            bf16x8 b0 = *reinterpret_cast<const bf16x8*>(ldsQ + (c) * LDR + d);
            bf16x8 b1 = *reinterpret_cast<const bf16x8*>(ldsQ + (32 + c) * LDR + d);
            acc00 = __builtin_amdgcn_mfma_f32_32x32x16_bf16(a0, b0, acc00, 0, 0, 0);
            acc01 = __builtin_amdgcn_mfma_f32_32x32x16_bf16(a0, b1, acc01, 0, 0, 0);
            acc10 = __builtin_amdgcn_mfma_f32_32x32x16_bf16(a1, b0, acc10, 0, 0, 0);
            acc11 = __builtin_amdgcn_mfma_f32_32x32x16_bf16(a1, b1, acc11, 0, 0, 0);
        }
        __syncthreads();
    }

    float* sigl = reinterpret_cast<float*>(lds);
#pragma unroll
    for (int i = 0; i < 4; ++i) {
        int idx = i * 256 + tid;
        *reinterpret_cast<float4*>(sigl + idx * 4) =
            *reinterpret_cast<const float4*>(sig + idx * 4);
    }
    __syncthreads();

    int p = qi * 256 + kg * 4 + w;
    float tmax0 = -FLT_MAX, tmax1 = -FLT_MAX;
    float smax[2][16];
#pragma unroll
    for (int si = 0; si < 2; ++si) {
        const floatx16& A0 = si ? acc10 : acc00;
        const floatx16& A1 = si ? acc11 : acc01;
#pragma unroll
        for (int r = 0; r < 16; ++r) {
            int srow = si * 32 + (r & 3) + 8 * (r >> 2) + 4 * h;
            float v0 = A0[r] * sigl[srow * 64 + c];
            float v1 = A1[r] * sigl[srow * 64 + 32 + c];
            tmax0 = fmaxf(tmax0, v0);
            tmax1 = fmaxf(tmax1, v1);
            smax[si][r] = fmaxf(v0, v1);
        }
    }
    tmax0 = fmaxf(tmax0, __shfl_xor(tmax0, 32, 64));
    tmax1 = fmaxf(tmax1, __shfl_xor(tmax1, 32, 64));
    if (h == 0) {
        xbuf[(size_t)(2 * p) * 64 + c] = tmax0;
        xbuf[(size_t)(2 * p) * 64 + 32 + c] = tmax1;
    }
#pragma unroll
    for (int stage = 1; stage < 32; stage <<= 1) {
#pragma unroll
        for (int si = 0; si < 2; ++si)
#pragma unroll
            for (int r = 0; r < 16; ++r)
                smax[si][r] = fmaxf(smax[si][r], __shfl_xor(smax[si][r], stage, 64));
    }
    if (c == 0) {
#pragma unroll
        for (int si = 0; si < 2; ++si)
#pragma unroll
            for (int r = 0; r < 16; ++r) {
                int srow = si * 32 + (r & 3) + 8 * (r >> 2) + 4 * h;
                xbuf[(size_t)(2 * p + 1) * 64 + srow] = smax[si][r];
            }
    }
}

// ---------------- K3: row stats S1[64], S2[64][64] over xbuf ---------------
__global__ __launch_bounds__(256) void k_stats1(const float* __restrict__ xbuf,
        double* __restrict__ S1d, double* __restrict__ S2d) {
    __shared__ float xr[4][64];
    int tid = threadIdx.x;
    int row0 = blockIdx.x * 256;
    float acc[16] = {};
    float s1 = 0.f;
    int pbase = tid * 16;
    for (int it = 0; it < 64; ++it) {
        int r = row0 + it * 4;
        xr[tid >> 6][tid & 63] = xbuf[(size_t)(r + (tid >> 6)) * 64 + (tid & 63)];
        __syncthreads();
#pragma unroll
        for (int e = 0; e < 16; ++e) {
            int a = (pbase + e) >> 6, b = (pbase + e) & 63;
            acc[e] += xr[0][a] * xr[0][b] + xr[1][a] * xr[1][b]
                    + xr[2][a] * xr[2][b] + xr[3][a] * xr[3][b];
        }
        if (tid < 64) s1 += xr[0][tid] + xr[1][tid] + xr[2][tid] + xr[3][tid];
        __syncthreads();
    }
#pragma unroll
    for (int e = 0; e < 16; ++e) atomicAdd(&S2d[pbase + e], (double)acc[e]);
    if (tid < 64) atomicAdd(&S1d[tid], (double)s1);
}

// ---------------- K4: finalize BN1 + normalized mean/cov -------------------
__global__ __launch_bounds__(256) void k_fin1(
        const double* __restrict__ S1d, const double* __restrict__ S2d,
        const float* __restrict__ g1, const float* __restrict__ be1,
        float* __restrict__ bn1, float* __restrict__ xbarn, float* __restrict__ covn) {
    int tid = threadIdx.x;
    double sum = 0.0, sumsq = 0.0;
    for (int j = 0; j < 64; ++j) { sum += S1d[j]; sumsq += S2d[j * 64 + j]; }
    const double Nall = (double)ROWSX * 64.0;
    double m1 = sum / Nall;
    double var1 = sumsq / Nall - m1 * m1;
    double scaled = (double)g1[0] / sqrt(var1 + 1e-5);
    if (tid == 0) { bn1[0] = (float)m1; bn1[1] = (float)scaled; }
    const double Rinv = 1.0 / (double)ROWSX;
    if (tid < 64) xbarn[tid] = (float)((S1d[tid] * Rinv - m1) * scaled) + be1[0];
#pragma unroll
    for (int e = 0; e < 16; ++e) {
        int idx = tid * 16 + e;
        int a = idx >> 6, b = idx & 63;
        double cov = S2d[idx] * Rinv - (S1d[a] * Rinv) * (S1d[b] * Rinv);
        covn[idx] = (float)(cov * scaled * scaled);
    }
}

// ---------------- K5: analytic BN2 constants per feature -------------------
// y_n[f] = alpha[f]*u[f] + beta[f],  u = x_n(bf16) @ W2b^T
// alpha = t2 = g2*rsqrt(var2+eps), var2 = W2b[f]^T Covn W2b[f]
// beta  = -t2*(W2b[f].xbarn) + be2   (b2 cancels through the mean-subtract)
__global__ __launch_bounds__(64) void k_bn2(
        const float* __restrict__ covn, const float* __restrict__ xbarn,
        const __hip_bfloat16* __restrict__ W2b,
        const float* __restrict__ g2, const float* __restrict__ be2,
        float* __restrict__ alpha, float* __restrict__ beta) {
    int f = blockIdx.x;
    int j = threadIdx.x;
    float wj = __bfloat162float(W2b[(size_t)f * 64 + j]);
    float t1 = 0.f;
    for (int b = 0; b < 64; ++b)
        t1 += covn[j * 64 + b] * __bfloat162float(W2b[(size_t)f * 64 + b]);
    float vc = wj * t1;
    float mc = wj * xbarn[j];
#pragma unroll
    for (int off = 32; off; off >>= 1) {
        vc += __shfl_down(vc, off);
        mc += __shfl_down(mc, off);
    }
    if (j == 0) {
        float t2 = g2[f] * rsqrtf(vc + 1e-5f);
        alpha[f] = t2;
        beta[f] = -t2 * mc + be2[f];
    }
}

// ---------------- K6: MFMA MLP: u = bf16(x_n) @ W2b^T, z = sum relu(a*u+b)*w3
// block = 128 rows, 4 waves of 32 rows; K=64 staged once; 16 chunks of 128 feats
__global__ __launch_bounds__(256, 2) void k_mlp_mfma(
        const float* __restrict__ xbuf, const float* __restrict__ bn1,
        const float* __restrict__ be1, const __hip_bfloat16* __restrict__ W2b,
        const float* __restrict__ alpha, const float* __restrict__ beta,
        const float* __restrict__ W3, const float* __restrict__ b3,
        float* __restrict__ z) {
    constexpr int LDR = 72;
    __shared__ __attribute__((aligned(16))) unsigned short Xs[128 * LDR]; // 18432 B
    __shared__ __attribute__((aligned(16))) unsigned short Ws[128 * LDR]; // 18432 B
    __shared__ float abw[3 * 128];
    const unsigned short* W2u = reinterpret_cast<const unsigned short*>(W2b);
    int tid = threadIdx.x;
    int w = tid >> 6, l = tid & 63, h = l >> 5, c = l & 31;
    int r0 = blockIdx.x * 128;
    float m1 = bn1[0], sc = bn1[1], sh = be1[0];

    // stage Xs = bf16(normalized xbuf rows r0..r0+127), 64 cols
#pragma unroll
    for (int i = 0; i < 4; ++i) {
        int id = i * 256 + tid;            // 0..1023
        int row = id >> 3, cg = id & 7;
        const float* src = xbuf + (size_t)(r0 + row) * 64 + cg * 8;
        float4 v0 = *reinterpret_cast<const float4*>(src);
        float4 v1 = *reinterpret_cast<const float4*>(src + 4);
        union { __hip_bfloat16 hh[8]; uint4 u; } o;
        o.hh[0] = __float2bfloat16((v0.x - m1) * sc + sh);
        o.hh[1] = __float2bfloat16((v0.y - m1) * sc + sh);
        o.hh[2] = __float2bfloat16((v0.z - m1) * sc + sh);
        o.hh[3] = __float2bfloat16((v0.w - m1) * sc + sh);
        o.hh[4] = __float2bfloat16((v1.x - m1) * sc + sh);
        o.hh[5] = __float2bfloat16((v1.y - m1) * sc + sh);
        o.hh[6] = __float2bfloat16((v1.z - m1) * sc + sh);
        o.hh[7] = __float2bfloat16((v1.w - m1) * sc + sh);
        *reinterpret_cast<uint4*>(&Xs[row * LDR + cg * 8]) = o.u;
    }

    float zacc[16] = {};
    for (int fc = 0; fc < FF / 128; ++fc) {
#pragma unroll
        for (int i = 0; i < 4; ++i) {
            int id = i * 256 + tid;
            int row = id >> 3, cg = id & 7;
            uint4 v = *reinterpret_cast<const uint4*>(W2u + (size_t)(fc * 128 + row) * 64 + cg * 8);
            *reinterpret_cast<uint4*>(&Ws[row * LDR + cg * 8]) = v;
        }
        if (tid < 128) {
            int f = fc * 128 + tid;
            abw[tid] = alpha[f];
            abw[128 + tid] = beta[f];
            abw[256 + tid] = W3[f];
        }
        __syncthreads();
        bf16x8 a[4];
#pragma unroll
        for (int st = 0; st < 4; ++st)
            a[st] = *reinterpret_cast<const bf16x8*>(&Xs[(w * 32 + c) * LDR + st * 16 + h * 8]);
#pragma unroll
        for (int nq = 0; nq < 4; ++nq) {
            floatx16 u = {};
#pragma unroll
            for (int st = 0; st < 4; ++st) {
                bf16x8 b = *reinterpret_cast<const bf16x8*>(&Ws[(nq * 32 + c) * LDR + st * 16 + h * 8]);
                u = __builtin_amdgcn_mfma_f32_32x32x16_bf16(a[st], b, u, 0, 0, 0);
            }
            float al = abw[nq * 32 + c];
            float bt = abw[128 + nq * 32 + c];
            float w3 = abw[256 + nq * 32 + c];
#pragma unroll
            for (int r = 0; r < 16; ++r)
                zacc[r] += fmaxf(al * u[r] + bt, 0.f) * w3;
        }
        __syncthreads();
    }
    // reduce over the 32 feature-lanes (butterfly within half; h encodes rows)
#pragma unroll
    for (int stage = 1; stage < 32; stage <<= 1)
#pragma unroll
        for (int r = 0; r < 16; ++r)
            zacc[r] += __shfl_xor(zacc[r], stage, 64);
    if (c == 0) {
        float bb = b3[0];
#pragma unroll
        for (int r = 0; r < 16; ++r) {
            int row = r0 + w * 32 + (r & 3) + 8 * (r >> 2) + 4 * h;
            z[row] = zacc[r] + bb;
        }
    }
}

// ---------------- K7: pair-sum + BN3 stats ---------------------------------
__global__ __launch_bounds__(256) void k_pair(const float* __restrict__ z,
        float* __restrict__ v, double* __restrict__ sums3) {
    int i = blockIdx.x * 256 + threadIdx.x;
    float val = z[2 * i] + z[2 * i + 1];
    v[i] = val;
    float s = val, ss = val * val;
#pragma unroll
    for (int off = 32; off; off >>= 1) {
        s += __shfl_down(s, off);
        ss += __shfl_down(ss, off);
    }
    __shared__ float bs[4], bss[4];
    int lane = threadIdx.x & 63, w = threadIdx.x >> 6;
    if (lane == 0) { bs[w] = s; bss[w] = ss; }
    __syncthreads();
    if (threadIdx.x == 0) {
        atomicAdd(&sums3[0], (double)(bs[0] + bs[1] + bs[2] + bs[3]));
        atomicAdd(&sums3[1], (double)(bss[0] + bss[1] + bss[2] + bss[3]));
    }
}

// ---------------- K8: finalize BN3 -----------------------------------------
__global__ void k_fin3(const double* __restrict__ sums3, const float* __restrict__ g3,
                       float* __restrict__ bn3) {
    double m = sums3[0] / (double)PAIRS;
    double var = sums3[1] / (double)PAIRS - m * m;
    bn3[0] = (float)m;
    bn3[1] = (float)((double)g3[0] / sqrt(var + 1e-5));
}

// ---------------- K9: write output -----------------------------------------
__global__ void k_out(const float* __restrict__ v, const float* __restrict__ bn3,
                      const float* __restrict__ be3, float* __restrict__ out) {
    int i = blockIdx.x * 256 + threadIdx.x;
    if (i < PAIRS) out[i] = (v[i] - bn3[0]) * bn3[1] + be3[0];
}

extern "C" void kernel_launch(void* const* d_in, const int* in_sizes, int n_in,
                              void* d_out, int out_size, void* d_ws, size_t ws_size,
                              hipStream_t stream) {
    (void)in_sizes; (void)n_in; (void)out_size; (void)ws_size;
    const float* tgt = (const float*)d_in[0];
    const float* mem = (const float*)d_in[1];
    const float* W1  = (const float*)d_in[2];
    const float* b1  = (const float*)d_in[3];
    const float* se  = (const float*)d_in[4];
    const float* W2  = (const float*)d_in[5];
    const float* b2  = (const float*)d_in[6];
    const float* W3  = (const float*)d_in[7];
    const float* b3  = (const float*)d_in[8];
    const float* g1  = (const float*)d_in[9];
    const float* be1 = (const float*)d_in[10];
    const float* g2  = (const float*)d_in[11];
    const float* be2 = (const float*)d_in[12];
    const float* g3  = (const float*)d_in[13];
    const float* be3 = (const float*)d_in[14];
    const int*  flag = (const int*)d_in[15];
    (void)b2;  // cancels analytically through BN2's mean-subtract
    float* out = (float*)d_out;

    char* ws = (char*)d_ws;
    size_t off = 0;
    auto alloc = [&](size_t bytes) -> void* {
        void* p = ws + off;
        off = (off + bytes + 255) & ~(size_t)255;
        return p;
    };
    float* sig   = (float*)alloc((size_t)SSZ * SSZ * 4);
    __hip_bfloat16* Xb  = (__hip_bfloat16*)alloc((size_t)NX * D * 2);   // 21 MB
    __hip_bfloat16* W1b = (__hip_bfloat16*)alloc((size_t)D * D * 2);    // 0.5 MB
    __hip_bfloat16* W2b = (__hip_bfloat16*)alloc((size_t)FF * 64 * 2);  // 0.25 MB
    __hip_bfloat16* QKb = (__hip_bfloat16*)alloc((size_t)NX * D * 2);   // 21 MB
    float* xbuf  = (float*)alloc((size_t)ROWSX * 64 * 4);               // 8 MB
    float* z     = (float*)alloc((size_t)ROWSX * 4);
    float* v     = (float*)alloc((size_t)PAIRS * 4);
    float* alpha = (float*)alloc((size_t)FF * 4);
    float* beta  = (float*)alloc((size_t)FF * 4);
    float* xbarn = (float*)alloc(64 * 4);
    float* covn  = (float*)alloc(64 * 64 * 4);
    float* bn1   = (float*)alloc(16);
    float* bn3   = (float*)alloc(16);
    size_t statsStart = off;
    double* S1d   = (double*)alloc(64 * 8);
    double* S2d   = (double*)alloc(64 * 64 * 8);
    double* sums3 = (double*)alloc(2 * 8);
    size_t statsEnd = off;

    hipMemsetAsync(ws + statsStart, 0, statsEnd - statsStart, stream);

    k_sig<<<16, 256, 0, stream>>>(se, flag, sig);
    constexpr int CVT4 = (NX * D + D * D + FF * 64) / 4;
    k_cvt<<<(CVT4 + 255) / 256, 256, 0, stream>>>(tgt, mem, W1, W2, Xb, W1b, W2b);
    k_gemm1_mfma<<<(NX / 128) * (D / 128), 256, 0, stream>>>(Xb, W1b, b1, flag, QKb);
    k_score_mfma<<<NQ * (NK / 4), 256, 0, stream>>>(QKb, sig, xbuf);
    k_stats1<<<128, 256, 0, stream>>>(xbuf, S1d, S2d);
    k_fin1<<<1, 256, 0, stream>>>(S1d, S2d, g1, be1, bn1, xbarn, covn);
    k_bn2<<<FF, 64, 0, stream>>>(covn, xbarn, W2b, g2, be2, alpha, beta);
    k_mlp_mfma<<<ROWSX / 128, 256, 0, stream>>>(xbuf, bn1, be1, W2b, alpha, beta, W3, b3, z);
    k_pair<<<PAIRS / 256, 256, 0, stream>>>(z, v, sums3);
    k_fin3<<<1, 1, 0, stream>>>(sums3, g3, bn3);
    k_out<<<PAIRS / 256, 256, 0, stream>>>(v, bn3, be3, out);
}

// Round 5
// 362.831 us; speedup vs baseline: 7.2048x; 1.0140x over previous
//
#include <hip/hip_runtime.h>
#include <hip/hip_bf16.h>
#include <math.h>
#include <float.h>

// dims
constexpr int NQ = 64, NK = 256, SSZ = 64, D = 512, FF = 2048;
constexpr int PAIRS = NQ * NK;          // 16384
constexpr int ROWSX = 2 * PAIRS;        // 32768
constexpr int NX = (NQ + NK) * SSZ;     // 20480 rows of X = [tgt;mem]

typedef __bf16 bf16x8 __attribute__((ext_vector_type(8)));
typedef float floatx16 __attribute__((ext_vector_type(16)));

// async global->LDS, 16 B per lane; LDS dest = wave-uniform base + lane*16
__device__ __forceinline__ void gl2lds16(const unsigned short* g, unsigned short* l) {
    __builtin_amdgcn_global_load_lds(
        (const __attribute__((address_space(1))) unsigned int*)(g),
        (__attribute__((address_space(3))) unsigned int*)(l),
        16, 0, 0);
}

// ---------------- K0: sigmoid of score_embed (or 1.0 if !flag) -------------
__global__ void k_sig(const float* __restrict__ se, const int* __restrict__ flag,
                      float* __restrict__ sig) {
    int i = blockIdx.x * blockDim.x + threadIdx.x;
    if (i < SSZ * SSZ) {
        sig[i] = (*flag) ? 1.0f / (1.0f + expf(-se[i])) : 1.0f;
    }
}

// ---------------- K0b: convert X=[tgt;mem], W1, W2 to bf16 -----------------
__global__ __launch_bounds__(256) void k_cvt(
        const float* __restrict__ tgt, const float* __restrict__ mem,
        const float* __restrict__ W1, const float* __restrict__ W2,
        __hip_bfloat16* __restrict__ Xb, __hip_bfloat16* __restrict__ W1b,
        __hip_bfloat16* __restrict__ W2b) {
    constexpr int T4 = NQ * SSZ * D / 4;   // tgt float4 count
    constexpr int X4 = NX * D / 4;         // X float4 count
    constexpr int W4 = D * D / 4;          // W1 float4 count
    constexpr int V4 = FF * 64 / 4;        // W2 float4 count
    int idx = blockIdx.x * 256 + threadIdx.x;
    if (idx >= X4 + W4 + V4) return;
    const float* src;
    __hip_bfloat16* dst;
    if (idx < T4)           { src = tgt + (size_t)idx * 4;             dst = Xb + (size_t)idx * 4; }
    else if (idx < X4)      { src = mem + (size_t)(idx - T4) * 4;      dst = Xb + (size_t)idx * 4; }
    else if (idx < X4 + W4) { src = W1 + (size_t)(idx - X4) * 4;       dst = W1b + (size_t)(idx - X4) * 4; }
    else                    { src = W2 + (size_t)(idx - X4 - W4) * 4;  dst = W2b + (size_t)(idx - X4 - W4) * 4; }
    float4 v = *reinterpret_cast<const float4*>(src);
    union { __hip_bfloat16 h[4]; uint2 u; } o;
    o.h[0] = __float2bfloat16(v.x); o.h[1] = __float2bfloat16(v.y);
    o.h[2] = __float2bfloat16(v.z); o.h[3] = __float2bfloat16(v.w);
    *reinterpret_cast<uint2*>(dst) = o.u;
}

// ---------------- K1: MFMA GEMM1: C = Xb @ W1b^T + b1 (bf16 out) -----------
// 128x128 tile; async global->LDS staging with XOR-swizzled source chunks.
// LDS layout: tile row = 64 bf16 (128 B = 8 chunks); slot (r, p) holds
// global chunk p ^ (r&7); read offset = ((st*2+h) ^ (c&7))*8 elems.
__global__ __launch_bounds__(256, 3) void k_gemm1_mfma(
        const __hip_bfloat16* __restrict__ Xb, const __hip_bfloat16* __restrict__ W1b,
        const float* __restrict__ b1, const int* __restrict__ flag,
        __hip_bfloat16* __restrict__ C) {
    __shared__ __attribute__((aligned(16))) unsigned short lds[2 * 128 * 64]; // 32 KB
    const unsigned short* Xu = reinterpret_cast<const unsigned short*>(Xb);
    const unsigned short* Wu = reinterpret_cast<const unsigned short*>(W1b);
    unsigned short* Cu = reinterpret_cast<unsigned short*>(C);

    int tid = threadIdx.x;
    int bm = blockIdx.x >> 2, bn = blockIdx.x & 3;
    int m0 = bm * 128, n0 = bn * 128;

    if (!(*flag)) {
#pragma unroll
        for (int i = 0; i < 8; ++i) {
            int id = i * 256 + tid;
            int row = id >> 4, ch = id & 15;
            uint4 v = *reinterpret_cast<const uint4*>(Xu + (size_t)(m0 + row) * D + n0 + ch * 8);
            *reinterpret_cast<uint4*>(Cu + (size_t)(m0 + row) * D + n0 + ch * 8) = v;
        }
        return;
    }

    int w = tid >> 6, l = tid & 63, h = l >> 5, c = l & 31;
    int wm = w >> 1, wn = w & 1;
    int chg = (l & 7) ^ (l >> 3);     // swizzled source chunk for this lane
    int cx = c & 7;
    floatx16 acc00 = {}, acc01 = {}, acc10 = {}, acc11 = {};

    for (int kb = 0; kb < D; kb += 64) {
#pragma unroll
        for (int j = 0; j < 8; ++j) {
            int i = w * 8 + j;              // 0..31
            int buf = i >> 4;               // 0: A(X), 1: B(W1)
            int rb = (i & 15) * 8;
            int r = rb + (l >> 3);
            const unsigned short* src = (buf == 0)
                ? (Xu + (size_t)(m0 + r) * D + kb + chg * 8)
                : (Wu + (size_t)(n0 + r) * D + kb + chg * 8);
            gl2lds16(src, lds + buf * 8192 + rb * 64);
        }
        __syncthreads();
        const unsigned short* pA = lds + (wm * 64) * 64;
        const unsigned short* pB = lds + 8192 + (wn * 64) * 64;
#pragma unroll
        for (int st = 0; st < 4; ++st) {
            int ko = ((st * 2 + h) ^ cx) * 8;
            bf16x8 a0 = *reinterpret_cast<const bf16x8*>(pA + c * 64 + ko);
            bf16x8 a1 = *reinterpret_cast<const bf16x8*>(pA + (32 + c) * 64 + ko);
            bf16x8 b0 = *reinterpret_cast<const bf16x8*>(pB + c * 64 + ko);
            bf16x8 b1 = *reinterpret_cast<const bf16x8*>(pB + (32 + c) * 64 + ko);
            acc00 = __builtin_amdgcn_mfma_f32_32x32x16_bf16(a0, b0, acc00, 0, 0, 0);
            acc01 = __builtin_amdgcn_mfma_f32_32x32x16_bf16(a0, b1, acc01, 0, 0, 0);
            acc10 = __builtin_amdgcn_mfma_f32_32x32x16_bf16(a1, b0, acc10, 0, 0, 0);
            acc11 = __builtin_amdgcn_mfma_f32_32x32x16_bf16(a1, b1, acc11, 0, 0, 0);
        }
        __syncthreads();
    }

    int mbase = m0 + wm * 64, nbase = n0 + wn * 64;
    float bia0 = b1[nbase + c], bia1 = b1[nbase + 32 + c];
#pragma unroll
    for (int mi = 0; mi < 2; ++mi) {
        const floatx16& A0 = mi ? acc10 : acc00;
        const floatx16& A1 = mi ? acc11 : acc01;
#pragma unroll
        for (int r = 0; r < 16; ++r) {
            int m = mbase + mi * 32 + (r & 3) + 8 * (r >> 2) + 4 * h;
            C[(size_t)m * D + nbase + c] = __float2bfloat16(A0[r] + bia0);
            C[(size_t)m * D + nbase + 32 + c] = __float2bfloat16(A1[r] + bia1);
        }
    }
}

// ---------------- K2: MFMA score einsum + sigmoid + dual max ---------------
// block = 4 waves; wave w handles pair p = qi*256 + (kg*4+w).
// Async staging + XOR swizzle as in k_gemm1_mfma. Tiles: 0 = Q, 1+w = K(w).
__global__ __launch_bounds__(256, 3) void k_score_mfma(
        const __hip_bfloat16* __restrict__ QKb, const float* __restrict__ sig,
        float* __restrict__ xbuf) {
    __shared__ __attribute__((aligned(16))) unsigned short lds[5 * 64 * 64]; // 40960 B
    const unsigned short* QKu = reinterpret_cast<const unsigned short*>(QKb);

    int tid = threadIdx.x;
    int w = tid >> 6;
    int l = tid & 63;
    int h = l >> 5;
    int c = l & 31;
    int chg = (l & 7) ^ (l >> 3);
    int cx = c & 7;

    int qi = blockIdx.x >> 6;
    int kg = blockIdx.x & 63;

    floatx16 acc00 = {}, acc01 = {}, acc10 = {}, acc11 = {};

    for (int kb = 0; kb < D; kb += 64) {
#pragma unroll
        for (int j = 0; j < 10; ++j) {
            int i = w * 10 + j;            // 0..39
            int t = i >> 3;                // tile 0..4
            int rb = (i & 7) * 8;
            int r = rb + (l >> 3);
            int grow = (t == 0) ? (qi * 64 + r)
                                : (NQ * SSZ + (kg * 4 + t - 1) * 64 + r);
            gl2lds16(QKu + (size_t)grow * D + kb + chg * 8,
                     lds + t * 4096 + rb * 64);
        }
        __syncthreads();
        const unsigned short* ldsQ = lds;
        const unsigned short* ldsK = lds + (1 + w) * 4096;
#pragma unroll
        for (int st = 0; st < 4; ++st) {
            int ko = ((st * 2 + h) ^ cx) * 8;
            bf16x8 a0 = *reinterpret_cast<const bf16x8*>(ldsK + c * 64 + ko);
            bf16x8 a1 = *reinterpret_cast<const bf16x8*>(ldsK + (32 + c) * 64 + ko);
            bf16x8 b0 = *reinterpret_cast<const bf16x8*>(ldsQ + c * 64 + ko);
            bf16x8 b1 = *reinterpret_cast<const bf16x8*>(ldsQ + (32 + c) * 64 + ko);
            acc00 = __builtin_amdgcn_mfma_f32_32x32x16_bf16(a0, b0, acc00, 0, 0, 0);
            acc01 = __builtin_amdgcn_mfma_f32_32x32x16_bf16(a0, b1, acc01, 0, 0, 0);
            acc10 = __builtin_amdgcn_mfma_f32_32x32x16_bf16(a1, b0, acc10, 0, 0, 0);
            acc11 = __builtin_amdgcn_mfma_f32_32x32x16_bf16(a1, b1, acc11, 0, 0, 0);
        }
        __syncthreads();
    }

    float* sigl = reinterpret_cast<float*>(lds);
#pragma unroll
    for (int i = 0; i < 4; ++i) {
        int idx = i * 256 + tid;
        *reinterpret_cast<float4*>(sigl + idx * 4) =
            *reinterpret_cast<const float4*>(sig + idx * 4);
    }
    __syncthreads();

    int p = qi * 256 + kg * 4 + w;
    float tmax0 = -FLT_MAX, tmax1 = -FLT_MAX;
    float smax[2][16];
#pragma unroll
    for (int si = 0; si < 2; ++si) {
        const floatx16& A0 = si ? acc10 : acc00;
        const floatx16& A1 = si ? acc11 : acc01;
#pragma unroll
        for (int r = 0; r < 16; ++r) {
            int srow = si * 32 + (r & 3) + 8 * (r >> 2) + 4 * h;
            float v0 = A0[r] * sigl[srow * 64 + c];
            float v1 = A1[r] * sigl[srow * 64 + 32 + c];
            tmax0 = fmaxf(tmax0, v0);
            tmax1 = fmaxf(tmax1, v1);
            smax[si][r] = fmaxf(v0, v1);
        }
    }
    tmax0 = fmaxf(tmax0, __shfl_xor(tmax0, 32, 64));
    tmax1 = fmaxf(tmax1, __shfl_xor(tmax1, 32, 64));
    if (h == 0) {
        xbuf[(size_t)(2 * p) * 64 + c] = tmax0;
        xbuf[(size_t)(2 * p) * 64 + 32 + c] = tmax1;
    }
#pragma unroll
    for (int stage = 1; stage < 32; stage <<= 1) {
#pragma unroll
        for (int si = 0; si < 2; ++si)
#pragma unroll
            for (int r = 0; r < 16; ++r)
                smax[si][r] = fmaxf(smax[si][r], __shfl_xor(smax[si][r], stage, 64));
    }
    if (c == 0) {
#pragma unroll
        for (int si = 0; si < 2; ++si)
#pragma unroll
            for (int r = 0; r < 16; ++r) {
                int srow = si * 32 + (r & 3) + 8 * (r >> 2) + 4 * h;
                xbuf[(size_t)(2 * p + 1) * 64 + srow] = smax[si][r];
            }
    }
}

// ---------------- K3: row stats S1[64], S2[64][64] over xbuf ---------------
__global__ __launch_bounds__(256) void k_stats1(const float* __restrict__ xbuf,
        double* __restrict__ S1d, double* __restrict__ S2d) {
    __shared__ float xr[4][64];
    int tid = threadIdx.x;
    int row0 = blockIdx.x * 256;
    float acc[16] = {};
    float s1 = 0.f;
    int pbase = tid * 16;
    for (int it = 0; it < 64; ++it) {
        int r = row0 + it * 4;
        xr[tid >> 6][tid & 63] = xbuf[(size_t)(r + (tid >> 6)) * 64 + (tid & 63)];
        __syncthreads();
#pragma unroll
        for (int e = 0; e < 16; ++e) {
            int a = (pbase + e) >> 6, b = (pbase + e) & 63;
            acc[e] += xr[0][a] * xr[0][b] + xr[1][a] * xr[1][b]
                    + xr[2][a] * xr[2][b] + xr[3][a] * xr[3][b];
        }
        if (tid < 64) s1 += xr[0][tid] + xr[1][tid] + xr[2][tid] + xr[3][tid];
        __syncthreads();
    }
#pragma unroll
    for (int e = 0; e < 16; ++e) atomicAdd(&S2d[pbase + e], (double)acc[e]);
    if (tid < 64) atomicAdd(&S1d[tid], (double)s1);
}

// ---------------- K4: finalize BN1 + normalized mean/cov -------------------
__global__ __launch_bounds__(256) void k_fin1(
        const double* __restrict__ S1d, const double* __restrict__ S2d,
        const float* __restrict__ g1, const float* __restrict__ be1,
        float* __restrict__ bn1, float* __restrict__ xbarn, float* __restrict__ covn) {
    int tid = threadIdx.x;
    double sum = 0.0, sumsq = 0.0;
    for (int j = 0; j < 64; ++j) { sum += S1d[j]; sumsq += S2d[j * 64 + j]; }
    const double Nall = (double)ROWSX * 64.0;
    double m1 = sum / Nall;
    double var1 = sumsq / Nall - m1 * m1;
    double scaled = (double)g1[0] / sqrt(var1 + 1e-5);
    if (tid == 0) { bn1[0] = (float)m1; bn1[1] = (float)scaled; }
    const double Rinv = 1.0 / (double)ROWSX;
    if (tid < 64) xbarn[tid] = (float)((S1d[tid] * Rinv - m1) * scaled) + be1[0];
#pragma unroll
    for (int e = 0; e < 16; ++e) {
        int idx = tid * 16 + e;
        int a = idx >> 6, b = idx & 63;
        double cov = S2d[idx] * Rinv - (S1d[a] * Rinv) * (S1d[b] * Rinv);
        covn[idx] = (float)(cov * scaled * scaled);
    }
}

// ---------------- K5: analytic BN2 constants per feature -------------------
__global__ __launch_bounds__(64) void k_bn2(
        const float* __restrict__ covn, const float* __restrict__ xbarn,
        const __hip_bfloat16* __restrict__ W2b,
        const float* __restrict__ g2, const float* __restrict__ be2,
        float* __restrict__ alpha, float* __restrict__ beta) {
    int f = blockIdx.x;
    int j = threadIdx.x;
    float wj = __bfloat162float(W2b[(size_t)f * 64 + j]);
    float t1 = 0.f;
    for (int b = 0; b < 64; ++b)
        t1 += covn[j * 64 + b] * __bfloat162float(W2b[(size_t)f * 64 + b]);
    float vc = wj * t1;
    float mc = wj * xbarn[j];
#pragma unroll
    for (int off = 32; off; off >>= 1) {
        vc += __shfl_down(vc, off);
        mc += __shfl_down(mc, off);
    }
    if (j == 0) {
        float t2 = g2[f] * rsqrtf(vc + 1e-5f);
        alpha[f] = t2;
        beta[f] = -t2 * mc + be2[f];
    }
}

// ---------------- K6: MFMA MLP: u = bf16(x_n) @ W2b^T, z = sum relu(a*u+b)*w3
__global__ __launch_bounds__(256, 2) void k_mlp_mfma(
        const float* __restrict__ xbuf, const float* __restrict__ bn1,
        const float* __restrict__ be1, const __hip_bfloat16* __restrict__ W2b,
        const float* __restrict__ alpha, const float* __restrict__ beta,
        const float* __restrict__ W3, const float* __restrict__ b3,
        float* __restrict__ z) {
    constexpr int LDR = 72;
    __shared__ __attribute__((aligned(16))) unsigned short Xs[128 * LDR];
    __shared__ __attribute__((aligned(16))) unsigned short Ws[128 * LDR];
    __shared__ float abw[3 * 128];
    const unsigned short* W2u = reinterpret_cast<const unsigned short*>(W2b);
    int tid = threadIdx.x;
    int w = tid >> 6, l = tid & 63, h = l >> 5, c = l & 31;
    int r0 = blockIdx.x * 128;
    float m1 = bn1[0], sc = bn1[1], sh = be1[0];

#pragma unroll
    for (int i = 0; i < 4; ++i) {
        int id = i * 256 + tid;
        int row = id >> 3, cg = id & 7;
        const float* src = xbuf + (size_t)(r0 + row) * 64 + cg * 8;
        float4 v0 = *reinterpret_cast<const float4*>(src);
        float4 v1 = *reinterpret_cast<const float4*>(src + 4);
        union { __hip_bfloat16 hh[8]; uint4 u; } o;
        o.hh[0] = __float2bfloat16((v0.x - m1) * sc + sh);
        o.hh[1] = __float2bfloat16((v0.y - m1) * sc + sh);
        o.hh[2] = __float2bfloat16((v0.z - m1) * sc + sh);
        o.hh[3] = __float2bfloat16((v0.w - m1) * sc + sh);
        o.hh[4] = __float2bfloat16((v1.x - m1) * sc + sh);
        o.hh[5] = __float2bfloat16((v1.y - m1) * sc + sh);
        o.hh[6] = __float2bfloat16((v1.z - m1) * sc + sh);
        o.hh[7] = __float2bfloat16((v1.w - m1) * sc + sh);
        *reinterpret_cast<uint4*>(&Xs[row * LDR + cg * 8]) = o.u;
    }

    float zacc[16] = {};
    for (int fc = 0; fc < FF / 128; ++fc) {
#pragma unroll
        for (int i = 0; i < 4; ++i) {
            int id = i * 256 + tid;
            int row = id >> 3, cg = id & 7;
            uint4 v = *reinterpret_cast<const uint4*>(W2u + (size_t)(fc * 128 + row) * 64 + cg * 8);
            *reinterpret_cast<uint4*>(&Ws[row * LDR + cg * 8]) = v;
        }
        if (tid < 128) {
            int f = fc * 128 + tid;
            abw[tid] = alpha[f];
            abw[128 + tid] = beta[f];
            abw[256 + tid] = W3[f];
        }
        __syncthreads();
        bf16x8 a[4];
#pragma unroll
        for (int st = 0; st < 4; ++st)
            a[st] = *reinterpret_cast<const bf16x8*>(&Xs[(w * 32 + c) * LDR + st * 16 + h * 8]);
#pragma unroll
        for (int nq = 0; nq < 4; ++nq) {
            floatx16 u = {};
#pragma unroll
            for (int st = 0; st < 4; ++st) {
                bf16x8 b = *reinterpret_cast<const bf16x8*>(&Ws[(nq * 32 + c) * LDR + st * 16 + h * 8]);
                u = __builtin_amdgcn_mfma_f32_32x32x16_bf16(a[st], b, u, 0, 0, 0);
            }
            float al = abw[nq * 32 + c];
            float bt = abw[128 + nq * 32 + c];
            float w3 = abw[256 + nq * 32 + c];
#pragma unroll
            for (int r = 0; r < 16; ++r)
                zacc[r] += fmaxf(al * u[r] + bt, 0.f) * w3;
        }
        __syncthreads();
    }
#pragma unroll
    for (int stage = 1; stage < 32; stage <<= 1)
#pragma unroll
        for (int r = 0; r < 16; ++r)
            zacc[r] += __shfl_xor(zacc[r], stage, 64);
    if (c == 0) {
        float bb = b3[0];
#pragma unroll
        for (int r = 0; r < 16; ++r) {
            int row = r0 + w * 32 + (r & 3) + 8 * (r >> 2) + 4 * h;
            z[row] = zacc[r] + bb;
        }
    }
}

// ---------------- K7: pair-sum + BN3 stats ---------------------------------
__global__ __launch_bounds__(256) void k_pair(const float* __restrict__ z,
        float* __restrict__ v, double* __restrict__ sums3) {
    int i = blockIdx.x * 256 + threadIdx.x;
    float val = z[2 * i] + z[2 * i + 1];
    v[i] = val;
    float s = val, ss = val * val;
#pragma unroll
    for (int off = 32; off; off >>= 1) {
        s += __shfl_down(s, off);
        ss += __shfl_down(ss, off);
    }
    __shared__ float bs[4], bss[4];
    int lane = threadIdx.x & 63, w = threadIdx.x >> 6;
    if (lane == 0) { bs[w] = s; bss[w] = ss; }
    __syncthreads();
    if (threadIdx.x == 0) {
        atomicAdd(&sums3[0], (double)(bs[0] + bs[1] + bs[2] + bs[3]));
        atomicAdd(&sums3[1], (double)(bss[0] + bss[1] + bss[2] + bss[3]));
    }
}

// ---------------- K8: finalize BN3 -----------------------------------------
__global__ void k_fin3(const double* __restrict__ sums3, const float* __restrict__ g3,
                       float* __restrict__ bn3) {
    double m = sums3[0] / (double)PAIRS;
    double var = sums3[1] / (double)PAIRS - m * m;
    bn3[0] = (float)m;
    bn3[1] = (float)((double)g3[0] / sqrt(var + 1e-5));
}

// ---------------- K9: write output -----------------------------------------
__global__ void k_out(const float* __restrict__ v, const float* __restrict__ bn3,
                      const float* __restrict__ be3, float* __restrict__ out) {
    int i = blockIdx.x * 256 + threadIdx.x;
    if (i < PAIRS) out[i] = (v[i] - bn3[0]) * bn3[1] + be3[0];
}

extern "C" void kernel_launch(void* const* d_in, const int* in_sizes, int n_in,
                              void* d_out, int out_size, void* d_ws, size_t ws_size,
                              hipStream_t stream) {
    (void)in_sizes; (void)n_in; (void)out_size; (void)ws_size;
    const float* tgt = (const float*)d_in[0];
    const float* mem = (const float*)d_in[1];
    const float* W1  = (const float*)d_in[2];
    const float* b1  = (const float*)d_in[3];
    const float* se  = (const float*)d_in[4];
    const float* W2  = (const float*)d_in[5];
    const float* b2  = (const float*)d_in[6];
    const float* W3  = (const float*)d_in[7];
    const float* b3  = (const float*)d_in[8];
    const float* g1  = (const float*)d_in[9];
    const float* be1 = (const float*)d_in[10];
    const float* g2  = (const float*)d_in[11];
    const float* be2 = (const float*)d_in[12];
    const float* g3  = (const float*)d_in[13];
    const float* be3 = (const float*)d_in[14];
    const int*  flag = (const int*)d_in[15];
    (void)b2;  // cancels analytically through BN2's mean-subtract
    float* out = (float*)d_out;

    char* ws = (char*)d_ws;
    size_t off = 0;
    auto alloc = [&](size_t bytes) -> void* {
        void* p = ws + off;
        off = (off + bytes + 255) & ~(size_t)255;
        return p;
    };
    float* sig   = (float*)alloc((size_t)SSZ * SSZ * 4);
    __hip_bfloat16* Xb  = (__hip_bfloat16*)alloc((size_t)NX * D * 2);   // 21 MB
    __hip_bfloat16* W1b = (__hip_bfloat16*)alloc((size_t)D * D * 2);    // 0.5 MB
    __hip_bfloat16* W2b = (__hip_bfloat16*)alloc((size_t)FF * 64 * 2);  // 0.25 MB
    __hip_bfloat16* QKb = (__hip_bfloat16*)alloc((size_t)NX * D * 2);   // 21 MB
    float* xbuf  = (float*)alloc((size_t)ROWSX * 64 * 4);               // 8 MB
    float* z     = (float*)alloc((size_t)ROWSX * 4);
    float* v     = (float*)alloc((size_t)PAIRS * 4);
    float* alpha = (float*)alloc((size_t)FF * 4);
    float* beta  = (float*)alloc((size_t)FF * 4);
    float* xbarn = (float*)alloc(64 * 4);
    float* covn  = (float*)alloc(64 * 64 * 4);
    float* bn1   = (float*)alloc(16);
    float* bn3   = (float*)alloc(16);
    size_t statsStart = off;
    double* S1d   = (double*)alloc(64 * 8);
    double* S2d   = (double*)alloc(64 * 64 * 8);
    double* sums3 = (double*)alloc(2 * 8);
    size_t statsEnd = off;

    hipMemsetAsync(ws + statsStart, 0, statsEnd - statsStart, stream);

    k_sig<<<16, 256, 0, stream>>>(se, flag, sig);
    constexpr int CVT4 = (NX * D + D * D + FF * 64) / 4;
    k_cvt<<<(CVT4 + 255) / 256, 256, 0, stream>>>(tgt, mem, W1, W2, Xb, W1b, W2b);
    k_gemm1_mfma<<<(NX / 128) * (D / 128), 256, 0, stream>>>(Xb, W1b, b1, flag, QKb);
    k_score_mfma<<<NQ * (NK / 4), 256, 0, stream>>>(QKb, sig, xbuf);
    k_stats1<<<128, 256, 0, stream>>>(xbuf, S1d, S2d);
    k_fin1<<<1, 256, 0, stream>>>(S1d, S2d, g1, be1, bn1, xbarn, covn);
    k_bn2<<<FF, 64, 0, stream>>>(covn, xbarn, W2b, g2, be2, alpha, beta);
    k_mlp_mfma<<<ROWSX / 128, 256, 0, stream>>>(xbuf, bn1, be1, W2b, alpha, beta, W3, b3, z);
    k_pair<<<PAIRS / 256, 256, 0, stream>>>(z, v, sums3);
    k_fin3<<<1, 1, 0, stream>>>(sums3, g3, bn3);
    k_out<<<PAIRS / 256, 256, 0, stream>>>(v, bn3, be3, out);
}